// Round 11
// baseline (400.172 us; speedup 1.0000x reference)
//
#include <hip/hip_runtime.h>
#include <hip/hip_bf16.h>

#define NN 50000
#define NE 800000
#define IND 128
#define NH 8
#define EBLK 256          // binning blocks
#define EPB 3125          // NE / EBLK
#define NBUK 391          // buckets of 128 dst nodes
#define NBUKP 392         // padded (bucket 391 empty -> offset == NE)
#define GH (NBUKP * EBLK) // 100352
#define PREPB 308         // prep blocks: 78848 / 256

typedef __hip_bfloat16 bf16;
typedef __attribute__((ext_vector_type(8))) short short8;
typedef __attribute__((ext_vector_type(8))) __bf16 bf16x8;
typedef __attribute__((ext_vector_type(4))) float floatx4;
typedef __attribute__((ext_vector_type(2))) float floatx2;

static __device__ __forceinline__ short f2bf_bits(float f) {
    unsigned u = __float_as_uint(f);
    u = (u + 0x7fffu + ((u >> 16) & 1u)) >> 16;
    return (short)u;
}
static __device__ __forceinline__ float bf2f(bf16 v) { return __bfloat162float(v); }
static __device__ __forceinline__ floatx2 up2(unsigned av) {
    floatx2 r;
    r.x = __uint_as_float(av << 16);
    r.y = __uint_as_float(av & 0xffff0000u);
    return r;
}
static __device__ __forceinline__ unsigned pk2(float a, float b) {
    return (unsigned)(unsigned short)f2bf_bits(a) | ((unsigned)(unsigned short)f2bf_bits(b) << 16);
}
// acc.lo += a.lo * al.lo ; acc.hi += a.hi * al.lo   (broadcast LOW half of al)
static __device__ __forceinline__ void pk_fma_lo(floatx2& acc, floatx2 a, floatx2 al) {
    asm("v_pk_fma_f32 %0, %1, %2, %0 op_sel:[0,0,0] op_sel_hi:[1,0,1]"
        : "+v"(acc) : "v"(a), "v"(al));
}
// acc.lo += a.lo * al.hi ; acc.hi += a.hi * al.hi   (broadcast HIGH half of al)
static __device__ __forceinline__ void pk_fma_hi(floatx2& acc, floatx2 a, floatx2 al) {
    asm("v_pk_fma_f32 %0, %1, %2, %0 op_sel:[0,1,0] op_sel_hi:[1,1,1]"
        : "+v"(acc) : "v"(a), "v"(al));
}

// exclusive scan of bsum[0..NBUKP) into gb[0..512); mirrors scang1's proven pattern
static __device__ __forceinline__ void scan_buckets(const int* __restrict__ bsum,
        int* sp, int* gb, int tid) {
    int v0 = (2 * tid < NBUKP) ? bsum[2 * tid] : 0;
    int v1 = (2 * tid + 1 < NBUKP) ? bsum[2 * tid + 1] : 0;
    int c = v0 + v1;
    sp[tid] = c; __syncthreads();
    int val = c;
#pragma unroll
    for (int off = 1; off < 256; off <<= 1) {
        int t = (tid >= off) ? sp[tid - off] : 0;
        __syncthreads();
        val += t; sp[tid] = val;
        __syncthreads();
    }
    int pex = val - c;
    gb[2 * tid] = pex;
    gb[2 * tid + 1] = pex + v0;
    __syncthreads();
}

// ---------------- merged: edge bin counting (blocks 0..255) + weight prep (blocks 256..563) ----
__global__ __launch_bounds__(256) void bin_count_prep_kernel(const int* __restrict__ edst,
        int* __restrict__ ghist,
        const float* __restrict__ gcn1_w, const float* __restrict__ gcn2_w,
        const float* __restrict__ gat1_w, const float* __restrict__ gat2_w,
        const float* __restrict__ as1, const float* __restrict__ ad1,
        const float* __restrict__ as2, const float* __restrict__ ad2,
        bf16* __restrict__ wT1, bf16* __restrict__ wT2,
        bf16* __restrict__ wgT1, bf16* __restrict__ wgT2,
        float* __restrict__ was1, float* __restrict__ wad1,
        float* __restrict__ was2, float* __restrict__ wad2) {
    __shared__ int hsh[NBUKP];
    const int tid = threadIdx.x;
    if (blockIdx.x < EBLK) {
        const int blk = blockIdx.x;
        for (int b = tid; b < NBUKP; b += 256) hsh[b] = 0;
        __syncthreads();
        const int e0 = blk * EPB;
        for (int e = e0 + tid; e < e0 + EPB; e += 256)
            atomicAdd(&hsh[edst[e] >> 7], 1);
        __syncthreads();
        for (int b = tid; b < NBUKP; b += 256)
            ghist[b * EBLK + blk] = hsh[b];
    } else {
        int idx = (blockIdx.x - EBLK) * 256 + tid;
        if (idx < 8192) {
            int m = idx >> 7, k = idx & 127;
            ((short*)wT1)[idx] = f2bf_bits(gcn1_w[(long)k * 64 + m]);
        } else if (idx < 12288) {
            int i = idx - 8192;
            int m = i >> 6, k = i & 63;
            ((short*)wT2)[i] = f2bf_bits(gcn2_w[(long)k * 64 + m]);
        } else if (idx < 45056) {
            int i = idx - 12288;
            int m = i >> 9, k = i & 511;
            int h = k >> 6, c = k & 63;
            ((short*)wgT1)[i] = f2bf_bits(gat1_w[(long)c * 512 + h * 64 + m]);
        } else if (idx < 77824) {
            int i = idx - 45056;
            int m = i >> 9, k = i & 511;
            int h = k >> 6, c = k & 63;
            ((short*)wgT2)[i] = (m < 32) ? f2bf_bits(gat2_w[(long)c * 256 + h * 32 + m]) : (short)0;
        } else if (idx < 78336) {
            int i = idx - 77824;
            int h = i >> 6, c = i & 63;
            const float* wrow = gat1_w + (long)c * 512 + h * 64;
            float s = 0.f, d = 0.f;
            for (int cc = 0; cc < 64; ++cc) {
                float w = wrow[cc];
                s += w * as1[h * 64 + cc];
                d += w * ad1[h * 64 + cc];
            }
            was1[i] = s; wad1[i] = d;
        } else if (idx < 78848) {
            int i = idx - 78336;
            int h = i >> 6, c = i & 63;
            const float* wrow = gat2_w + (long)c * 256 + h * 32;
            float s = 0.f, d = 0.f;
            for (int cc = 0; cc < 32; ++cc) {
                float w = wrow[cc];
                s += w * as2[h * 32 + cc];
                d += w * ad2[h * 32 + cc];
            }
            was2[i] = s; wad2[i] = d;
        }
    }
}

__global__ __launch_bounds__(256) void scang1_kernel(const int* __restrict__ src,
        int* __restrict__ pre, int* __restrict__ bsum, int n) {
    __shared__ int sh[256];
    const int tid = threadIdx.x;
    const int idx = blockIdx.x * 256 + tid;
    int c = (idx < n) ? src[idx] : 0;
    sh[tid] = c; __syncthreads();
    int val = c;
#pragma unroll
    for (int off = 1; off < 256; off <<= 1) {
        int t = (tid >= off) ? sh[tid - off] : 0;
        __syncthreads();
        val += t; sh[tid] = val;
        __syncthreads();
    }
    if (idx < n) pre[idx] = val - c;
    if (tid == 255) bsum[blockIdx.x] = val;
}

// bin_scatter inlines the bucket-level scan (scang2 kernel removed)
__global__ __launch_bounds__(256) void bin_scatter_kernel(const int* __restrict__ esrc,
        const int* __restrict__ edst, const int* __restrict__ gpre,
        const int* __restrict__ bsum, unsigned* __restrict__ ebuf) {
    __shared__ int cur[NBUKP];
    __shared__ int sp[256], gb[512];
    const int tid = threadIdx.x, blk = blockIdx.x;
    scan_buckets(bsum, sp, gb, tid);
    for (int b = tid; b < NBUKP; b += 256)
        cur[b] = gpre[b * EBLK + blk] + gb[b];
    __syncthreads();
    const int e0 = blk * EPB;
    for (int e = e0 + tid; e < e0 + EPB; e += 256) {
        int d = edst[e], s = esrc[e];
        int pos = atomicAdd(&cur[d >> 7], 1);
        ebuf[pos] = ((unsigned)(d & 127) << 16) | (unsigned)s;
    }
}

__global__ __launch_bounds__(256) void bucket_finalize_kernel(const unsigned* __restrict__ ebuf,
        const int* __restrict__ gpre, const int* __restrict__ bsum,
        int* __restrict__ rowptr, float* __restrict__ dinv, int* __restrict__ csrc) {
    __shared__ int lh[128], lcur[128], sc[256];
    __shared__ int sp[256], gb[512];
    const int bu = blockIdx.x, tid = threadIdx.x;
    scan_buckets(bsum, sp, gb, tid);
    const int seg_beg = gpre[bu * EBLK] + gb[bu];
    const int seg_end = gpre[(bu + 1) * EBLK] + gb[bu + 1];
    if (tid < 128) lh[tid] = 0;
    __syncthreads();
    for (int i = seg_beg + tid; i < seg_end; i += 256)
        atomicAdd(&lh[ebuf[i] >> 16], 1);
    __syncthreads();
    int c = (tid < 128) ? lh[tid] : 0;
    sc[tid] = c; __syncthreads();
    int val = c;
#pragma unroll
    for (int off = 1; off < 256; off <<= 1) {
        int t = (tid >= off) ? sc[tid - off] : 0;
        __syncthreads();
        val += t; sc[tid] = val;
        __syncthreads();
    }
    int excl = val - c;
    if (tid < 128) {
        lcur[tid] = excl;
        int node = bu * 128 + tid;
        if (node < NN) {
            rowptr[node] = seg_beg + excl;
            dinv[node] = rsqrtf((float)c + 1.f);
        }
    }
    if (bu == 0 && tid == 0) rowptr[NN] = NE;
    __syncthreads();
    for (int i = seg_beg + tid; i < seg_end; i += 256) {
        unsigned u = ebuf[i];
        int pos = atomicAdd(&lcur[u >> 16], 1);
        csrc[seg_beg + pos] = (int)(u & 0xffffu);
    }
}

// ---------------- MFMA matmul v2: NO LDS ----------------
template<int K, int EPI, bool AF32>
__global__ __launch_bounds__(256) void mm2_kernel(const void* __restrict__ A,
        const bf16* __restrict__ wT, void* __restrict__ C,
        const float* __restrict__ bias, const float* __restrict__ rowscale,
        int nrows, int M) {
    const int row0 = blockIdx.x * 64;
    const int tid = threadIdx.x;
    const int lane = tid & 63, wave = tid >> 6;
    const int lr = lane & 15, q = lane >> 4;
    const int row = row0 + wave * 16 + lr;
    const bool rok = row < nrows;
    constexpr int NC = 4;
    floatx4 acc[NC] = {};
#pragma unroll 4
    for (int k0 = 0; k0 < K; k0 += 32) {
        short8 av = {0, 0, 0, 0, 0, 0, 0, 0};
        if (rok) {
            if (AF32) {
                const float* apf = (const float*)A + (long)row * K + q * 8 + k0;
                floatx4 va = *(const floatx4*)apf;
                floatx4 vb = *(const floatx4*)(apf + 4);
#pragma unroll
                for (int j = 0; j < 4; ++j) { av[j] = f2bf_bits(va[j]); av[4 + j] = f2bf_bits(vb[j]); }
            } else {
                av = *(const short8*)((const short*)A + (long)row * K + q * 8 + k0);
            }
        }
        bf16x8 a = __builtin_bit_cast(bf16x8, av);
#pragma unroll
        for (int c = 0; c < NC; ++c) {
            bf16x8 b = __builtin_bit_cast(bf16x8,
                *(const short8*)((const short*)wT + (long)(c * 16 + lr) * K + k0 + q * 8));
            acc[c] = __builtin_amdgcn_mfma_f32_16x16x32_bf16(a, b, acc[c], 0, 0, 0);
        }
    }
#pragma unroll
    for (int c = 0; c < NC; ++c)
#pragma unroll
        for (int r = 0; r < 4; ++r) {
            int orow = row0 + wave * 16 + q * 4 + r;
            int col = c * 16 + lr;
            if (orow < nrows && col < M) {
                long o = (long)orow * M + col;
                float v = acc[c][r];
                if (EPI == 0) ((float*)C)[o] = v;
                else if (EPI == 2) {
                    v = v * 0.125f + bias[col];
                    ((bf16*)C)[o] = __float2bfloat16(fmaxf(v, 0.f));
                } else {
                    ((bf16*)C)[o] = __float2bfloat16(rowscale[orow] * v);
                }
            }
        }
}

// ---------------- fused GCN aggregate + bias + BN + ReLU (8-deep batched gather) ----------------
__global__ __launch_bounds__(256) void gcn_fused_kernel(const int* __restrict__ rowptr,
        const int* __restrict__ csrc, const float* __restrict__ dinv,
        const bf16* __restrict__ hin, const float* __restrict__ b,
        const float* __restrict__ gamma, const float* __restrict__ beta,
        const float* __restrict__ mean, const float* __restrict__ var,
        bf16* __restrict__ actout) {
    const int node = blockIdx.x * 4 + (threadIdx.x >> 6);
    if (node >= NN) return;
    const int lane = threadIdx.x & 63;
    const int eslot = lane >> 5, cp = lane & 31;
    const unsigned cpo = 4u * (unsigned)cp;
    const int beg = __builtin_amdgcn_readfirstlane(rowptr[node]);
    const int end = __builtin_amdgcn_readfirstlane(rowptr[node + 1]);
    const float di = dinv[node];
    const int* csp = csrc + beg;
    floatx2 acc2 = {0.f, 0.f};
    const int dn = end - beg;
    const int kup = (dn + 15) & ~15;
    for (int k0 = 0; k0 < kup; k0 += 16) {
        int s_[8]; float w_[8];
#pragma unroll
        for (int u = 0; u < 8; ++u) {
            int k = k0 + 2 * u + eslot;
            int ok = k < dn;
            s_[u] = csp[ok ? k : 0];
            w_[u] = ok ? 1.f : 0.f;
        }
        unsigned av_[8];
#pragma unroll
        for (int u = 0; u < 8; ++u)
            av_[u] = *(const unsigned*)((const char*)hin + ((unsigned)s_[u] * 128u + cpo));
#pragma unroll
        for (int u = 0; u < 8; ++u) {
            floatx2 a2 = up2(av_[u]);
            acc2 += a2 * w_[u];
        }
    }
    acc2.x += __shfl_xor(acc2.x, 32);
    acc2.y += __shfl_xor(acc2.y, 32);
    {
        unsigned sv = *(const unsigned*)((const char*)hin + ((unsigned)node * 128u + cpo));
        acc2 += up2(sv);
    }
    int c0 = 2 * cp, c1 = c0 + 1;
    float x0 = acc2.x * di + b[c0];
    float x1 = acc2.y * di + b[c1];
    x0 = (x0 - mean[c0]) * rsqrtf(var[c0] + 1e-5f) * gamma[c0] + beta[c0];
    x1 = (x1 - mean[c1]) * rsqrtf(var[c1] + 1e-5f) * gamma[c1] + beta[c1];
    if (eslot == 0)
        *(unsigned*)((unsigned short*)actout + (long)node * 64 + c0) =
            pk2(fmaxf(x0, 0.f), fmaxf(x1, 0.f));
}

// es[n,h] = <act[n,:], was[h,:]>
__global__ __launch_bounds__(256) void scores_kernel(const bf16* __restrict__ actb,
        const float* __restrict__ was, const float* __restrict__ wad,
        float* __restrict__ es, float* __restrict__ ed, int n) {
    const int node = blockIdx.x * 4 + (threadIdx.x >> 6);
    if (node >= n) return;
    const int lane = threadIdx.x & 63;
    const int h = lane >> 3, cg = lane & 7;
    short8 a8 = *(const short8*)((const short*)actb + (long)node * 64 + cg * 8);
    const float* wsp = was + h * 64 + cg * 8;
    const float* wdp = wad + h * 64 + cg * 8;
    floatx4 ws0 = *(const floatx4*)wsp, ws1 = *(const floatx4*)(wsp + 4);
    floatx4 wd0 = *(const floatx4*)wdp, wd1 = *(const floatx4*)(wdp + 4);
    float s = 0.f, d = 0.f;
#pragma unroll
    for (int j = 0; j < 4; ++j) {
        float v0 = bf2f(__builtin_bit_cast(bf16, a8[j]));
        float v1 = bf2f(__builtin_bit_cast(bf16, a8[4 + j]));
        s += v0 * ws0[j] + v1 * ws1[j];
        d += v0 * wd0[j] + v1 * wd1[j];
    }
#pragma unroll
    for (int off = 1; off < 8; off <<= 1) {
        s += __shfl_xor(s, off);
        d += __shfl_xor(d, off);
    }
    if (cg == 0) { es[node * NH + h] = s; ed[node * NH + h] = d; }
}

// ---------------- FUSED GAT v3: 16 waves, 1 node/wave + K-SPLIT projection -------------------
// 1024 threads = 16 waves; 16 nodes/block (unsorted, R8 lineage). Aggregation identical to R8.
// Projection: wave (ct = wv>>2, kq = wv&3) computes col-tile ct over K-quarter kq -> 4 MFMAs
// per wave, ALL 16 waves active (GAT1). Weight fragments prefetched into registers BEFORE the
// barrier (independent of aggt) so post-barrier path is 4 ds_read + 4 MFMA. Partials staged in
// LDS (reusing salpha space, dead after aggregation) and reduced by waves wv<NCT.
// NCT: 4 -> M=64 GAT1; 2 -> M=32 GAT2. EPI: 2 = bias+relu bf16; 4 = bias+logsoftmax f32.
template<int NCT, int EPI>
__global__ __launch_bounds__(1024) void gat_fused_kernel(const int* __restrict__ rowptr,
        const int* __restrict__ csrc, const float* __restrict__ es, const float* __restrict__ ed,
        const bf16* __restrict__ actb, const bf16* __restrict__ wgT,
        const float* __restrict__ bias, void* __restrict__ outp) {
    __shared__ __align__(16) float salpha[16][512];          // reused as partials after agg
    __shared__ int ssrcs[16][64];
    __shared__ __align__(16) float sself[16][8];
    __shared__ __align__(16) unsigned short aggt[16][520];   // all 16 rows live
    __shared__ float redbuf[2][2][16];                        // [max|sum][ct][row]
    const int wv = threadIdx.x >> 6;
    const int lane = threadIdx.x & 63;
    const int h = lane & 7, slot = lane >> 3;
    const int hq = lane >> 5, cp = lane & 31;
    const unsigned cpo = 4u * (unsigned)cp;

    // ================= aggregation: ONE node per wave (R8-proven body) =================
    const int node = blockIdx.x * 16 + wv;
    const int beg = __builtin_amdgcn_readfirstlane(rowptr[node]);
    const int end = __builtin_amdgcn_readfirstlane(rowptr[node + 1]);
    const int deg = end - beg;
    const int* csp = csrc + beg;
    const float edr = *(const float*)((const char*)ed + ((unsigned)node * 32u + (unsigned)h * 4u));
    float selfe = *(const float*)((const char*)es + ((unsigned)node * 32u + (unsigned)h * 4u)) + edr;
    selfe = selfe > 0.f ? selfe : 0.2f * selfe;

    // ---- projection geometry + weight prefetch (independent of aggregation results) ----
    const int lr = lane & 15, q = lane >> 4;
    const int ct = wv >> 2, kq = wv & 3;
    const bool pact = ct < NCT;
    bf16x8 bfrag0, bfrag1, bfrag2, bfrag3;
    if (pact) {
        const short* wp = (const short*)wgT + (long)(ct * 16 + lr) * 512 + kq * 128 + q * 8;
        bfrag0 = __builtin_bit_cast(bf16x8, *(const short8*)(wp));
        bfrag1 = __builtin_bit_cast(bf16x8, *(const short8*)(wp + 32));
        bfrag2 = __builtin_bit_cast(bf16x8, *(const short8*)(wp + 64));
        bfrag3 = __builtin_bit_cast(bf16x8, *(const short8*)(wp + 96));
    }

    if (deg <= 64) {
        // ---- Phase A: independent clamped gathers, uniform-branch block skip ----
        const int nb = (deg + 7) >> 3;
        const int dm1 = (deg > 0) ? deg - 1 : 0;
        float ex_r[8]; int s_r[8];
        float den = 0.f;
#pragma unroll
        for (int b = 0; b < 8; ++b) { ex_r[b] = 0.f; s_r[b] = 0; }
        if (deg > 0) {
#pragma unroll
            for (int b = 0; b < 8; ++b)
                if (b < nb) {
                    int k = b * 8 + slot;
                    s_r[b] = csp[k < deg ? k : dm1];
                }
#pragma unroll
            for (int b = 0; b < 8; ++b)
                if (b < nb) {
                    float e = *(const float*)((const char*)es +
                              ((unsigned)s_r[b] * 32u + (unsigned)h * 4u)) + edr;
                    e = e > 0.f ? e : 0.2f * e;
                    float ex = __expf(e - selfe);
                    ex_r[b] = (b * 8 + slot < deg) ? ex : 0.f;
                    den += ex_r[b];
                }
        }
        den += __shfl_xor(den, 8);
        den += __shfl_xor(den, 16);
        den += __shfl_xor(den, 32);
        const float invden = 1.f / (den + 1.f);
#pragma unroll
        for (int b = 0; b < 8; ++b)
            if (b < nb) salpha[wv][b * 64 + lane] = ex_r[b] * invden;
        if (h == 0) {
#pragma unroll
            for (int b = 0; b < 8; ++b)
                if (b < nb) ssrcs[wv][b * 8 + slot] = s_r[b];
        }
        if (slot == 0) sself[wv][h] = invden;

        // ---- Phase B: (head-quad, channel-pair) gather, pipelined 8-edge groups ----
        floatx2 acc2[4] = {};
        const int ng = nb;
        if (ng > 0) {
            int sA0, sA1, sA2, sA3, sA4, sA5, sA6, sA7;
            int sB0, sB1, sB2, sB3, sB4, sB5, sB6, sB7;
            unsigned rA0, rA1, rA2, rA3, rA4, rA5, rA6, rA7;
            unsigned rB0, rB1, rB2, rB3, rB4, rB5, rB6, rB7;
#define LOAD_BANK(S, R, G) do { \
    const int* sp_ = &ssrcs[wv][(G) * 8]; \
    S##0 = sp_[0]; S##1 = sp_[1]; S##2 = sp_[2]; S##3 = sp_[3]; \
    S##4 = sp_[4]; S##5 = sp_[5]; S##6 = sp_[6]; S##7 = sp_[7]; \
    R##0 = *(const unsigned*)((const char*)actb + ((unsigned)S##0 * 128u + cpo)); \
    R##1 = *(const unsigned*)((const char*)actb + ((unsigned)S##1 * 128u + cpo)); \
    R##2 = *(const unsigned*)((const char*)actb + ((unsigned)S##2 * 128u + cpo)); \
    R##3 = *(const unsigned*)((const char*)actb + ((unsigned)S##3 * 128u + cpo)); \
    R##4 = *(const unsigned*)((const char*)actb + ((unsigned)S##4 * 128u + cpo)); \
    R##5 = *(const unsigned*)((const char*)actb + ((unsigned)S##5 * 128u + cpo)); \
    R##6 = *(const unsigned*)((const char*)actb + ((unsigned)S##6 * 128u + cpo)); \
    R##7 = *(const unsigned*)((const char*)actb + ((unsigned)S##7 * 128u + cpo)); \
} while (0)
#define FMA_BANK(R, G) do { \
    const float* ab_ = &salpha[wv][(G) * 64 + hq * 4]; \
    unsigned rr_[8] = {R##0, R##1, R##2, R##3, R##4, R##5, R##6, R##7}; \
    _Pragma("unroll") \
    for (int j_ = 0; j_ < 8; ++j_) { \
        floatx4 al_ = *(const floatx4*)(ab_ + j_ * 8); \
        floatx2 al01_ = __builtin_shufflevector(al_, al_, 0, 1); \
        floatx2 al23_ = __builtin_shufflevector(al_, al_, 2, 3); \
        floatx2 a2_ = up2(rr_[j_]); \
        pk_fma_lo(acc2[0], a2_, al01_); pk_fma_hi(acc2[1], a2_, al01_); \
        pk_fma_lo(acc2[2], a2_, al23_); pk_fma_hi(acc2[3], a2_, al23_); \
    } \
} while (0)
            LOAD_BANK(sA, rA, 0);
            int g = 0;
            while (true) {
                if (g + 1 < ng) LOAD_BANK(sB, rB, g + 1);
                FMA_BANK(rA, g);
                ++g; if (g >= ng) break;
                if (g + 1 < ng) LOAD_BANK(sA, rA, g + 1);
                FMA_BANK(rB, g);
                ++g; if (g >= ng) break;
            }
#undef LOAD_BANK
#undef FMA_BANK
        }
        {   // self edge
            unsigned sv = *(const unsigned*)((const char*)actb + ((unsigned)node * 128u + cpo));
            floatx2 a2 = up2(sv);
            floatx4 sa = *(const floatx4*)&sself[wv][hq * 4];
            floatx2 sa01 = __builtin_shufflevector(sa, sa, 0, 1);
            floatx2 sa23 = __builtin_shufflevector(sa, sa, 2, 3);
            pk_fma_lo(acc2[0], a2, sa01); pk_fma_hi(acc2[1], a2, sa01);
            pk_fma_lo(acc2[2], a2, sa23); pk_fma_hi(acc2[3], a2, sa23);
        }
        // stage to LDS agg row: k = (hq*4+j)*64 + 2cp
#pragma unroll
        for (int j = 0; j < 4; ++j)
            *(unsigned*)&aggt[wv][(hq * 4 + j) * 64 + 2 * cp] = pk2(acc2[j].x, acc2[j].y);
    } else {
        // ---- fallback (deg>64, rare): streaming two-pass, full-wave per edge ----
        float acc[NH] = {0.f, 0.f, 0.f, 0.f, 0.f, 0.f, 0.f, 0.f};
        float den = 0.f;
        for (int base = beg; base < end; base += 8) {
            int ei = base + slot;
            if (ei < end) {
                int s = csrc[ei];
                float e = es[s * NH + h] + edr;
                e = e > 0.f ? e : 0.2f * e;
                den += __expf(e - selfe);
            }
        }
        den += __shfl_xor(den, 8);
        den += __shfl_xor(den, 16);
        den += __shfl_xor(den, 32);
        const float invden = 1.f / (den + 1.f);
        for (int base = beg; base < end; base += 8) {
            int ei = base + slot;
            float al = 0.f; int sl = 0;
            if (ei < end) {
                sl = csrc[ei];
                float e = es[sl * NH + h] + edr;
                e = e > 0.f ? e : 0.2f * e;
                al = __expf(e - selfe) * invden;
            }
            salpha[wv][lane] = al;
            if (h == 0) ssrcs[wv][slot] = sl;
            int ecnt = end - base; if (ecnt > 8) ecnt = 8;
            for (int j = 0; j < ecnt; ++j) {
                int s = ssrcs[wv][j];
                float a = bf2f(actb[(long)s * 64 + lane]);
                floatx4 al0 = *(const floatx4*)&salpha[wv][j * 8];
                floatx4 al1 = *(const floatx4*)&salpha[wv][j * 8 + 4];
                acc[0] += al0[0] * a; acc[1] += al0[1] * a;
                acc[2] += al0[2] * a; acc[3] += al0[3] * a;
                acc[4] += al1[0] * a; acc[5] += al1[1] * a;
                acc[6] += al1[2] * a; acc[7] += al1[3] * a;
            }
        }
        {
            if (slot == 0) sself[wv][h] = invden;
            float a = bf2f(actb[(long)node * 64 + lane]);
            floatx4 s0 = *(const floatx4*)&sself[wv][0];
            floatx4 s1 = *(const floatx4*)&sself[wv][4];
            acc[0] += s0[0] * a; acc[1] += s0[1] * a;
            acc[2] += s0[2] * a; acc[3] += s0[3] * a;
            acc[4] += s1[0] * a; acc[5] += s1[1] * a;
            acc[6] += s1[2] * a; acc[7] += s1[3] * a;
        }
#pragma unroll
        for (int hh = 0; hh < NH; ++hh)
            aggt[wv][hh * 64 + lane] = (unsigned short)f2bf_bits(acc[hh]);
    }

    __syncthreads();

    // ================= K-split MFMA projection: all 16 waves active =================
    // wave (ct,kq): col-tile ct, K in [kq*128, kq*128+128); 4 MFMAs; partial -> LDS.
    float* paggr = &salpha[0][0];            // reuse dead salpha: [16][256] floats
    floatx4 acc = {};
    if (pact) {
        const int kb = kq * 128 + q * 8;
        bf16x8 a0 = __builtin_bit_cast(bf16x8, *(const short8*)&aggt[lr][kb]);
        bf16x8 a1 = __builtin_bit_cast(bf16x8, *(const short8*)&aggt[lr][kb + 32]);
        bf16x8 a2 = __builtin_bit_cast(bf16x8, *(const short8*)&aggt[lr][kb + 64]);
        bf16x8 a3 = __builtin_bit_cast(bf16x8, *(const short8*)&aggt[lr][kb + 96]);
        acc = __builtin_amdgcn_mfma_f32_16x16x32_bf16(a0, bfrag0, acc, 0, 0, 0);
        acc = __builtin_amdgcn_mfma_f32_16x16x32_bf16(a1, bfrag1, acc, 0, 0, 0);
        acc = __builtin_amdgcn_mfma_f32_16x16x32_bf16(a2, bfrag2, acc, 0, 0, 0);
        acc = __builtin_amdgcn_mfma_f32_16x16x32_bf16(a3, bfrag3, acc, 0, 0, 0);
        *(floatx4*)&paggr[wv * 256 + lane * 4] = acc;
    }
    __syncthreads();
    // reduce K-quarters on waves wv < NCT (wv == ct here)
    if (wv < NCT) {
        floatx4 r0 = *(const floatx4*)&paggr[(wv * 4 + 0) * 256 + lane * 4];
        floatx4 r1 = *(const floatx4*)&paggr[(wv * 4 + 1) * 256 + lane * 4];
        floatx4 r2 = *(const floatx4*)&paggr[(wv * 4 + 2) * 256 + lane * 4];
        floatx4 r3 = *(const floatx4*)&paggr[(wv * 4 + 3) * 256 + lane * 4];
        acc = (r0 + r1) + (r2 + r3);
    }
    const bool act = wv < NCT;

    if (EPI == 2) {
        if (act) {
#pragma unroll
            for (int r = 0; r < 4; ++r) {
                int onode = blockIdx.x * 16 + q * 4 + r;
                int col = wv * 16 + lr;
                float v = acc[r] * 0.125f + bias[col];
                ((bf16*)outp)[(long)onode * 64 + col] = __float2bfloat16(fmaxf(v, 0.f));
            }
        }
    } else {
        // log_softmax across 32 cols held by waves 0 (cols 0-15) and 1 (cols 16-31)
        float v[4], m[4];
#pragma unroll
        for (int r = 0; r < 4; ++r) {
            v[r] = acc[r] * 0.125f + (act ? bias[wv * 16 + lr] : 0.f);
            m[r] = v[r];
        }
#pragma unroll
        for (int off = 1; off < 16; off <<= 1)
#pragma unroll
            for (int r = 0; r < 4; ++r) m[r] = fmaxf(m[r], __shfl_xor(m[r], off));
        if (act && lr == 0) {
#pragma unroll
            for (int r = 0; r < 4; ++r) redbuf[0][wv][q * 4 + r] = m[r];
        }
        __syncthreads();
        float s[4];
#pragma unroll
        for (int r = 0; r < 4; ++r) {
            float mm_ = fmaxf(redbuf[0][0][q * 4 + r], redbuf[0][1][q * 4 + r]);
            m[r] = mm_;
            s[r] = act ? __expf(v[r] - mm_) : 0.f;
        }
#pragma unroll
        for (int off = 1; off < 16; off <<= 1)
#pragma unroll
            for (int r = 0; r < 4; ++r) s[r] += __shfl_xor(s[r], off);
        if (act && lr == 0) {
#pragma unroll
            for (int r = 0; r < 4; ++r) redbuf[1][wv][q * 4 + r] = s[r];
        }
        __syncthreads();
        if (act) {
#pragma unroll
            for (int r = 0; r < 4; ++r) {
                int row = q * 4 + r;
                int onode = blockIdx.x * 16 + row;
                float ls = m[r] + logf(redbuf[1][0][row] + redbuf[1][1][row]);
                ((float*)outp)[(long)onode * 32 + wv * 16 + lr] = v[r] - ls;
            }
        }
    }
}

// ---------------- launch ----------------
extern "C" void kernel_launch(void* const* d_in, const int* in_sizes, int n_in,
                              void* d_out, int out_size, void* d_ws, size_t ws_size,
                              hipStream_t stream) {
    const float* x        = (const float*)d_in[0];
    const int*   eidx     = (const int*)d_in[1];
    const float* gcn1_w   = (const float*)d_in[2];
    const float* gcn1_b   = (const float*)d_in[3];
    const float* bn1_g    = (const float*)d_in[4];
    const float* bn1_b    = (const float*)d_in[5];
    const float* bn1_m    = (const float*)d_in[6];
    const float* bn1_v    = (const float*)d_in[7];
    const float* gat1_w   = (const float*)d_in[8];
    const float* gat1_as  = (const float*)d_in[9];
    const float* gat1_ad  = (const float*)d_in[10];
    const float* gat1_b   = (const float*)d_in[11];
    const float* gcn2_w   = (const float*)d_in[12];
    const float* gcn2_b   = (const float*)d_in[13];
    const float* bn2_g    = (const float*)d_in[14];
    const float* bn2_b    = (const float*)d_in[15];
    const float* bn2_m    = (const float*)d_in[16];
    const float* bn2_v    = (const float*)d_in[17];
    const float* gat2_w   = (const float*)d_in[18];
    const float* gat2_as  = (const float*)d_in[19];
    const float* gat2_ad  = (const float*)d_in[20];
    const float* gat2_b   = (const float*)d_in[21];
    float* out = (float*)d_out;

    const int* esrc = eidx;
    const int* edst = eidx + NE;

    // workspace (~78 MB, < proven-safe 110.6 MB)
    float* ws = (float*)d_ws;
    int*      ghist  = (int*)ws;                        // GH
    int*      gpre   = ghist + GH;                      // GH
    int*      gbsum  = gpre + GH;                       // 512 (unscanned block sums)
    unsigned* ebuf   = (unsigned*)(gbsum + 512);        // NE
    int*      rowptr = (int*)(ebuf + NE);               // 50048
    int*      csrc   = rowptr + 50048;                  // NE
    float*    dinv   = (float*)(csrc + NE);             // 50048
    float*    es     = dinv + 50048;                    // 400000
    float*    ed     = es + 400000;                     // 400000
    float*    was1   = ed + 400000;                     // 512
    float*    wad1   = was1 + 512;                      // 512
    float*    was2   = wad1 + 512;                      // 512
    float*    wad2   = was2 + 512;                      // 512
    bf16*     wT1    = (bf16*)(wad2 + 512);             // 64*128
    bf16*     wT2    = wT1 + 64 * 128;                  // 64*64
    bf16*     wgT1   = wT2 + 64 * 64;                   // 64*512
    bf16*     wgT2   = wgT1 + 64 * 512;                 // 64*512
    bf16*     actb   = wgT2 + 64 * 512;                 // N*64 bf16
    bf16*     mmbf   = actb + (size_t)NN * 64;          // N*64 bf16
    bf16*     gact   = mmbf + (size_t)NN * 64;          // N*64 bf16

    auto cdiv = [](long a, long b) { return (int)((a + b - 1) / b); };
    const int GB = cdiv(NN, 64);
    const int NB = cdiv(NN, 4);
    const int FB = NN / 16;   // 3125 exact

    // ---- CSR build ----
    bin_count_prep_kernel<<<EBLK + PREPB, 256, 0, stream>>>(edst, ghist,
        gcn1_w, gcn2_w, gat1_w, gat2_w, gat1_as, gat1_ad, gat2_as, gat2_ad,
        wT1, wT2, wgT1, wgT2, was1, wad1, was2, wad2);
    scang1_kernel<<<GH / 256, 256, 0, stream>>>(ghist, gpre, gbsum, GH);
    bin_scatter_kernel<<<EBLK, 256, 0, stream>>>(esrc, edst, gpre, gbsum, ebuf);
    bucket_finalize_kernel<<<NBUK, 256, 0, stream>>>(ebuf, gpre, gbsum, rowptr, dinv, csrc);

    // ---- GCN1 ----
    mm2_kernel<IND, 3, true><<<GB, 256, 0, stream>>>(x, wT1, mmbf, nullptr, dinv, NN, 64);
    gcn_fused_kernel<<<NB, 256, 0, stream>>>(rowptr, csrc, dinv, mmbf,
        gcn1_b, bn1_g, bn1_b, bn1_m, bn1_v, actb);

    // ---- GAT1 (C=64), fully fused, K-split projection ----
    scores_kernel<<<NB, 256, 0, stream>>>(actb, was1, wad1, es, ed, NN);
    gat_fused_kernel<4, 2><<<FB, 1024, 0, stream>>>(rowptr, csrc, es, ed, actb, wgT1, gat1_b, gact);

    // ---- GCN2 ----
    mm2_kernel<64, 3, false><<<GB, 256, 0, stream>>>(gact, wT2, mmbf, nullptr, dinv, NN, 64);
    gcn_fused_kernel<<<NB, 256, 0, stream>>>(rowptr, csrc, dinv, mmbf,
        gcn2_b, bn2_g, bn2_b, bn2_m, bn2_v, actb);

    // ---- GAT2 (C=32) + fused log_softmax -> out ----
    scores_kernel<<<NB, 256, 0, stream>>>(actb, was2, wad2, es, ed, NN);
    gat_fused_kernel<2, 4><<<FB, 1024, 0, stream>>>(rowptr, csrc, es, ed, actb, wgT2, gat2_b, out);
}

// Round 12
// 354.931 us; speedup vs baseline: 1.1275x; 1.1275x over previous
//
#include <hip/hip_runtime.h>
#include <hip/hip_bf16.h>

#define NN 50000
#define NE 800000
#define IND 128
#define NH 8
#define EBLK 256          // binning blocks
#define EPB 3125          // NE / EBLK
#define NBUK 391          // buckets of 128 dst nodes
#define NBUKP 392         // padded (bucket 391 empty -> offset == NE)
#define GH (NBUKP * EBLK) // 100352
#define PREPB 308         // prep blocks: 78848 / 256

typedef __hip_bfloat16 bf16;
typedef __attribute__((ext_vector_type(8))) short short8;
typedef __attribute__((ext_vector_type(8))) __bf16 bf16x8;
typedef __attribute__((ext_vector_type(4))) float floatx4;
typedef __attribute__((ext_vector_type(2))) float floatx2;

static __device__ __forceinline__ short f2bf_bits(float f) {
    unsigned u = __float_as_uint(f);
    u = (u + 0x7fffu + ((u >> 16) & 1u)) >> 16;
    return (short)u;
}
static __device__ __forceinline__ float bf2f(bf16 v) { return __bfloat162float(v); }
static __device__ __forceinline__ floatx2 up2(unsigned av) {
    floatx2 r;
    r.x = __uint_as_float(av << 16);
    r.y = __uint_as_float(av & 0xffff0000u);
    return r;
}
static __device__ __forceinline__ unsigned pk2(float a, float b) {
    return (unsigned)(unsigned short)f2bf_bits(a) | ((unsigned)(unsigned short)f2bf_bits(b) << 16);
}
// acc.lo += a.lo * al.lo ; acc.hi += a.hi * al.lo   (broadcast LOW half of al)
static __device__ __forceinline__ void pk_fma_lo(floatx2& acc, floatx2 a, floatx2 al) {
    asm("v_pk_fma_f32 %0, %1, %2, %0 op_sel:[0,0,0] op_sel_hi:[1,0,1]"
        : "+v"(acc) : "v"(a), "v"(al));
}
// acc.lo += a.lo * al.hi ; acc.hi += a.hi * al.hi   (broadcast HIGH half of al)
static __device__ __forceinline__ void pk_fma_hi(floatx2& acc, floatx2 a, floatx2 al) {
    asm("v_pk_fma_f32 %0, %1, %2, %0 op_sel:[0,1,0] op_sel_hi:[1,1,1]"
        : "+v"(acc) : "v"(a), "v"(al));
}

// exclusive scan of bsum[0..NBUKP) into gb[0..512); mirrors scang1's proven pattern
static __device__ __forceinline__ void scan_buckets(const int* __restrict__ bsum,
        int* sp, int* gb, int tid) {
    int v0 = (2 * tid < NBUKP) ? bsum[2 * tid] : 0;
    int v1 = (2 * tid + 1 < NBUKP) ? bsum[2 * tid + 1] : 0;
    int c = v0 + v1;
    sp[tid] = c; __syncthreads();
    int val = c;
#pragma unroll
    for (int off = 1; off < 256; off <<= 1) {
        int t = (tid >= off) ? sp[tid - off] : 0;
        __syncthreads();
        val += t; sp[tid] = val;
        __syncthreads();
    }
    int pex = val - c;
    gb[2 * tid] = pex;
    gb[2 * tid + 1] = pex + v0;
    __syncthreads();
}

// ---------------- merged: edge bin counting (blocks 0..255) + weight prep (blocks 256..563) ----
__global__ __launch_bounds__(256) void bin_count_prep_kernel(const int* __restrict__ edst,
        int* __restrict__ ghist,
        const float* __restrict__ gcn1_w, const float* __restrict__ gcn2_w,
        const float* __restrict__ gat1_w, const float* __restrict__ gat2_w,
        const float* __restrict__ as1, const float* __restrict__ ad1,
        const float* __restrict__ as2, const float* __restrict__ ad2,
        bf16* __restrict__ wT1, bf16* __restrict__ wT2,
        bf16* __restrict__ wgT1, bf16* __restrict__ wgT2,
        float* __restrict__ was1, float* __restrict__ wad1,
        float* __restrict__ was2, float* __restrict__ wad2) {
    __shared__ int hsh[NBUKP];
    const int tid = threadIdx.x;
    if (blockIdx.x < EBLK) {
        const int blk = blockIdx.x;
        for (int b = tid; b < NBUKP; b += 256) hsh[b] = 0;
        __syncthreads();
        const int e0 = blk * EPB;
        for (int e = e0 + tid; e < e0 + EPB; e += 256)
            atomicAdd(&hsh[edst[e] >> 7], 1);
        __syncthreads();
        for (int b = tid; b < NBUKP; b += 256)
            ghist[b * EBLK + blk] = hsh[b];
    } else {
        int idx = (blockIdx.x - EBLK) * 256 + tid;
        if (idx < 8192) {
            int m = idx >> 7, k = idx & 127;
            ((short*)wT1)[idx] = f2bf_bits(gcn1_w[(long)k * 64 + m]);
        } else if (idx < 12288) {
            int i = idx - 8192;
            int m = i >> 6, k = i & 63;
            ((short*)wT2)[i] = f2bf_bits(gcn2_w[(long)k * 64 + m]);
        } else if (idx < 45056) {
            int i = idx - 12288;
            int m = i >> 9, k = i & 511;
            int h = k >> 6, c = k & 63;
            ((short*)wgT1)[i] = f2bf_bits(gat1_w[(long)c * 512 + h * 64 + m]);
        } else if (idx < 77824) {
            int i = idx - 45056;
            int m = i >> 9, k = i & 511;
            int h = k >> 6, c = k & 63;
            ((short*)wgT2)[i] = (m < 32) ? f2bf_bits(gat2_w[(long)c * 256 + h * 32 + m]) : (short)0;
        } else if (idx < 78336) {
            int i = idx - 77824;
            int h = i >> 6, c = i & 63;
            const float* wrow = gat1_w + (long)c * 512 + h * 64;
            float s = 0.f, d = 0.f;
            for (int cc = 0; cc < 64; ++cc) {
                float w = wrow[cc];
                s += w * as1[h * 64 + cc];
                d += w * ad1[h * 64 + cc];
            }
            was1[i] = s; wad1[i] = d;
        } else if (idx < 78848) {
            int i = idx - 78336;
            int h = i >> 6, c = i & 63;
            const float* wrow = gat2_w + (long)c * 256 + h * 32;
            float s = 0.f, d = 0.f;
            for (int cc = 0; cc < 32; ++cc) {
                float w = wrow[cc];
                s += w * as2[h * 32 + cc];
                d += w * ad2[h * 32 + cc];
            }
            was2[i] = s; wad2[i] = d;
        }
    }
}

__global__ __launch_bounds__(256) void scang1_kernel(const int* __restrict__ src,
        int* __restrict__ pre, int* __restrict__ bsum, int n) {
    __shared__ int sh[256];
    const int tid = threadIdx.x;
    const int idx = blockIdx.x * 256 + tid;
    int c = (idx < n) ? src[idx] : 0;
    sh[tid] = c; __syncthreads();
    int val = c;
#pragma unroll
    for (int off = 1; off < 256; off <<= 1) {
        int t = (tid >= off) ? sh[tid - off] : 0;
        __syncthreads();
        val += t; sh[tid] = val;
        __syncthreads();
    }
    if (idx < n) pre[idx] = val - c;
    if (tid == 255) bsum[blockIdx.x] = val;
}

// bin_scatter inlines the bucket-level scan (scang2 kernel removed)
__global__ __launch_bounds__(256) void bin_scatter_kernel(const int* __restrict__ esrc,
        const int* __restrict__ edst, const int* __restrict__ gpre,
        const int* __restrict__ bsum, unsigned* __restrict__ ebuf) {
    __shared__ int cur[NBUKP];
    __shared__ int sp[256], gb[512];
    const int tid = threadIdx.x, blk = blockIdx.x;
    scan_buckets(bsum, sp, gb, tid);
    for (int b = tid; b < NBUKP; b += 256)
        cur[b] = gpre[b * EBLK + blk] + gb[b];
    __syncthreads();
    const int e0 = blk * EPB;
    for (int e = e0 + tid; e < e0 + EPB; e += 256) {
        int d = edst[e], s = esrc[e];
        int pos = atomicAdd(&cur[d >> 7], 1);
        ebuf[pos] = ((unsigned)(d & 127) << 16) | (unsigned)s;
    }
}

__global__ __launch_bounds__(256) void bucket_finalize_kernel(const unsigned* __restrict__ ebuf,
        const int* __restrict__ gpre, const int* __restrict__ bsum,
        int* __restrict__ rowptr, float* __restrict__ dinv, int* __restrict__ csrc) {
    __shared__ int lh[128], lcur[128], sc[256];
    __shared__ int sp[256], gb[512];
    const int bu = blockIdx.x, tid = threadIdx.x;
    scan_buckets(bsum, sp, gb, tid);
    const int seg_beg = gpre[bu * EBLK] + gb[bu];
    const int seg_end = gpre[(bu + 1) * EBLK] + gb[bu + 1];
    if (tid < 128) lh[tid] = 0;
    __syncthreads();
    for (int i = seg_beg + tid; i < seg_end; i += 256)
        atomicAdd(&lh[ebuf[i] >> 16], 1);
    __syncthreads();
    int c = (tid < 128) ? lh[tid] : 0;
    sc[tid] = c; __syncthreads();
    int val = c;
#pragma unroll
    for (int off = 1; off < 256; off <<= 1) {
        int t = (tid >= off) ? sc[tid - off] : 0;
        __syncthreads();
        val += t; sc[tid] = val;
        __syncthreads();
    }
    int excl = val - c;
    if (tid < 128) {
        lcur[tid] = excl;
        int node = bu * 128 + tid;
        if (node < NN) {
            rowptr[node] = seg_beg + excl;
            dinv[node] = rsqrtf((float)c + 1.f);
        }
    }
    if (bu == 0 && tid == 0) rowptr[NN] = NE;
    __syncthreads();
    for (int i = seg_beg + tid; i < seg_end; i += 256) {
        unsigned u = ebuf[i];
        int pos = atomicAdd(&lcur[u >> 16], 1);
        csrc[seg_beg + pos] = (int)(u & 0xffffu);
    }
}

// ---------------- MFMA matmul v2: NO LDS ----------------
template<int K, int EPI, bool AF32>
__global__ __launch_bounds__(256) void mm2_kernel(const void* __restrict__ A,
        const bf16* __restrict__ wT, void* __restrict__ C,
        const float* __restrict__ bias, const float* __restrict__ rowscale,
        int nrows, int M) {
    const int row0 = blockIdx.x * 64;
    const int tid = threadIdx.x;
    const int lane = tid & 63, wave = tid >> 6;
    const int lr = lane & 15, q = lane >> 4;
    const int row = row0 + wave * 16 + lr;
    const bool rok = row < nrows;
    constexpr int NC = 4;
    floatx4 acc[NC] = {};
#pragma unroll 4
    for (int k0 = 0; k0 < K; k0 += 32) {
        short8 av = {0, 0, 0, 0, 0, 0, 0, 0};
        if (rok) {
            if (AF32) {
                const float* apf = (const float*)A + (long)row * K + q * 8 + k0;
                floatx4 va = *(const floatx4*)apf;
                floatx4 vb = *(const floatx4*)(apf + 4);
#pragma unroll
                for (int j = 0; j < 4; ++j) { av[j] = f2bf_bits(va[j]); av[4 + j] = f2bf_bits(vb[j]); }
            } else {
                av = *(const short8*)((const short*)A + (long)row * K + q * 8 + k0);
            }
        }
        bf16x8 a = __builtin_bit_cast(bf16x8, av);
#pragma unroll
        for (int c = 0; c < NC; ++c) {
            bf16x8 b = __builtin_bit_cast(bf16x8,
                *(const short8*)((const short*)wT + (long)(c * 16 + lr) * K + k0 + q * 8));
            acc[c] = __builtin_amdgcn_mfma_f32_16x16x32_bf16(a, b, acc[c], 0, 0, 0);
        }
    }
#pragma unroll
    for (int c = 0; c < NC; ++c)
#pragma unroll
        for (int r = 0; r < 4; ++r) {
            int orow = row0 + wave * 16 + q * 4 + r;
            int col = c * 16 + lr;
            if (orow < nrows && col < M) {
                long o = (long)orow * M + col;
                float v = acc[c][r];
                if (EPI == 0) ((float*)C)[o] = v;
                else if (EPI == 2) {
                    v = v * 0.125f + bias[col];
                    ((bf16*)C)[o] = __float2bfloat16(fmaxf(v, 0.f));
                } else {
                    ((bf16*)C)[o] = __float2bfloat16(rowscale[orow] * v);
                }
            }
        }
}

// -------- fused GCN aggregate + bias + BN + ReLU + GAT SCORES (es/ed) --------
// After the cross-half reduce both 32-lane halves hold the full activation; eslot 0
// computes es (was), eslot 1 computes ed (wad), via LDS-staged score weights.
__global__ __launch_bounds__(256) void gcn_fused_kernel(const int* __restrict__ rowptr,
        const int* __restrict__ csrc, const float* __restrict__ dinv,
        const bf16* __restrict__ hin, const float* __restrict__ b,
        const float* __restrict__ gamma, const float* __restrict__ beta,
        const float* __restrict__ mean, const float* __restrict__ var,
        const float* __restrict__ was, const float* __restrict__ wad,
        bf16* __restrict__ actout, float* __restrict__ es, float* __restrict__ ed) {
    __shared__ float swd[1024];   // [0..511] was, [512..1023] wad
    const int tid = threadIdx.x;
    for (int i = tid; i < 1024; i += 256)
        swd[i] = (i < 512) ? was[i] : wad[i - 512];
    __syncthreads();
    const int node = blockIdx.x * 4 + (tid >> 6);
    const int lane = tid & 63;
    const int eslot = lane >> 5, cp = lane & 31;
    const unsigned cpo = 4u * (unsigned)cp;
    const int beg = __builtin_amdgcn_readfirstlane(rowptr[node]);
    const int end = __builtin_amdgcn_readfirstlane(rowptr[node + 1]);
    const float di = dinv[node];
    const int* csp = csrc + beg;
    floatx2 acc2 = {0.f, 0.f};
    const int dn = end - beg;
    const int kup = (dn + 15) & ~15;
    for (int k0 = 0; k0 < kup; k0 += 16) {
        int s_[8]; float w_[8];
#pragma unroll
        for (int u = 0; u < 8; ++u) {
            int k = k0 + 2 * u + eslot;
            int ok = k < dn;
            s_[u] = csp[ok ? k : 0];
            w_[u] = ok ? 1.f : 0.f;
        }
        unsigned av_[8];
#pragma unroll
        for (int u = 0; u < 8; ++u)
            av_[u] = *(const unsigned*)((const char*)hin + ((unsigned)s_[u] * 128u + cpo));
#pragma unroll
        for (int u = 0; u < 8; ++u) {
            floatx2 a2 = up2(av_[u]);
            acc2 += a2 * w_[u];
        }
    }
    acc2.x += __shfl_xor(acc2.x, 32);
    acc2.y += __shfl_xor(acc2.y, 32);
    {
        unsigned sv = *(const unsigned*)((const char*)hin + ((unsigned)node * 128u + cpo));
        acc2 += up2(sv);
    }
    int c0 = 2 * cp, c1 = c0 + 1;
    float x0 = acc2.x * di + b[c0];
    float x1 = acc2.y * di + b[c1];
    x0 = (x0 - mean[c0]) * rsqrtf(var[c0] + 1e-5f) * gamma[c0] + beta[c0];
    x1 = (x1 - mean[c1]) * rsqrtf(var[c1] + 1e-5f) * gamma[c1] + beta[c1];
    float x0r = fmaxf(x0, 0.f), x1r = fmaxf(x1, 0.f);
    if (eslot == 0)
        *(unsigned*)((unsigned short*)actout + (long)node * 64 + c0) = pk2(x0r, x1r);
    // ---- fused scores: p[h] = sum_c act[c]*w[h*64+c]; eslot 0 -> es, eslot 1 -> ed ----
    const float* wsel = &swd[eslot << 9];
    float p0, p1, p2, p3, p4, p5, p6, p7;
    {
        floatx2 w;
#define SC(H, P) w = *(const floatx2*)&wsel[H * 64 + c0]; P = x0r * w.x + x1r * w.y;
        SC(0, p0) SC(1, p1) SC(2, p2) SC(3, p3) SC(4, p4) SC(5, p5) SC(6, p6) SC(7, p7)
#undef SC
    }
#pragma unroll
    for (int off = 1; off < 32; off <<= 1) {
        p0 += __shfl_xor(p0, off); p1 += __shfl_xor(p1, off);
        p2 += __shfl_xor(p2, off); p3 += __shfl_xor(p3, off);
        p4 += __shfl_xor(p4, off); p5 += __shfl_xor(p5, off);
        p6 += __shfl_xor(p6, off); p7 += __shfl_xor(p7, off);
    }
    if (cp == 0) {
        float* dst = eslot ? ed : es;
        floatx4 v0 = {p0, p1, p2, p3}, v1 = {p4, p5, p6, p7};
        *(floatx4*)&dst[(long)node * 8] = v0;
        *(floatx4*)&dst[(long)node * 8 + 4] = v1;
    }
}

// ---------------- FUSED GAT: 16 waves, 1 node/wave + full 16-row MFMA projection ----------------
// (R8-proven structure, verbatim)
template<int NCT, int EPI>
__global__ __launch_bounds__(1024) void gat_fused_kernel(const int* __restrict__ rowptr,
        const int* __restrict__ csrc, const float* __restrict__ es, const float* __restrict__ ed,
        const bf16* __restrict__ actb, const bf16* __restrict__ wgT,
        const float* __restrict__ bias, void* __restrict__ outp) {
    __shared__ __align__(16) float salpha[16][512];
    __shared__ int ssrcs[16][64];
    __shared__ __align__(16) float sself[16][8];
    __shared__ __align__(16) unsigned short aggt[16][520];   // all 16 rows live
    __shared__ float redbuf[2][2][16];                        // [max|sum][ct][row]
    const int wv = threadIdx.x >> 6;
    const int lane = threadIdx.x & 63;
    const int h = lane & 7, slot = lane >> 3;
    const int hq = lane >> 5, cp = lane & 31;
    const unsigned cpo = 4u * (unsigned)cp;

    // ================= aggregation: ONE node per wave =================
    const int node = blockIdx.x * 16 + wv;
    const int beg = __builtin_amdgcn_readfirstlane(rowptr[node]);
    const int end = __builtin_amdgcn_readfirstlane(rowptr[node + 1]);
    const int deg = end - beg;
    const int* csp = csrc + beg;
    const float edr = *(const float*)((const char*)ed + ((unsigned)node * 32u + (unsigned)h * 4u));
    float selfe = *(const float*)((const char*)es + ((unsigned)node * 32u + (unsigned)h * 4u)) + edr;
    selfe = selfe > 0.f ? selfe : 0.2f * selfe;

    if (deg <= 64) {
        // ---- Phase A: independent clamped gathers, uniform-branch block skip ----
        const int nb = (deg + 7) >> 3;
        const int dm1 = (deg > 0) ? deg - 1 : 0;
        float ex_r[8]; int s_r[8];
        float den = 0.f;
#pragma unroll
        for (int b = 0; b < 8; ++b) { ex_r[b] = 0.f; s_r[b] = 0; }
        if (deg > 0) {
#pragma unroll
            for (int b = 0; b < 8; ++b)
                if (b < nb) {
                    int k = b * 8 + slot;
                    s_r[b] = csp[k < deg ? k : dm1];
                }
#pragma unroll
            for (int b = 0; b < 8; ++b)
                if (b < nb) {
                    float e = *(const float*)((const char*)es +
                              ((unsigned)s_r[b] * 32u + (unsigned)h * 4u)) + edr;
                    e = e > 0.f ? e : 0.2f * e;
                    float ex = __expf(e - selfe);
                    ex_r[b] = (b * 8 + slot < deg) ? ex : 0.f;
                    den += ex_r[b];
                }
        }
        den += __shfl_xor(den, 8);
        den += __shfl_xor(den, 16);
        den += __shfl_xor(den, 32);
        const float invden = 1.f / (den + 1.f);
#pragma unroll
        for (int b = 0; b < 8; ++b)
            if (b < nb) salpha[wv][b * 64 + lane] = ex_r[b] * invden;
        if (h == 0) {
#pragma unroll
            for (int b = 0; b < 8; ++b)
                if (b < nb) ssrcs[wv][b * 8 + slot] = s_r[b];
        }
        if (slot == 0) sself[wv][h] = invden;

        // ---- Phase B: (head-quad, channel-pair) gather, pipelined 8-edge groups ----
        floatx2 acc2[4] = {};
        const int ng = nb;
        if (ng > 0) {
            int sA0, sA1, sA2, sA3, sA4, sA5, sA6, sA7;
            int sB0, sB1, sB2, sB3, sB4, sB5, sB6, sB7;
            unsigned rA0, rA1, rA2, rA3, rA4, rA5, rA6, rA7;
            unsigned rB0, rB1, rB2, rB3, rB4, rB5, rB6, rB7;
#define LOAD_BANK(S, R, G) do { \
    const int* sp_ = &ssrcs[wv][(G) * 8]; \
    S##0 = sp_[0]; S##1 = sp_[1]; S##2 = sp_[2]; S##3 = sp_[3]; \
    S##4 = sp_[4]; S##5 = sp_[5]; S##6 = sp_[6]; S##7 = sp_[7]; \
    R##0 = *(const unsigned*)((const char*)actb + ((unsigned)S##0 * 128u + cpo)); \
    R##1 = *(const unsigned*)((const char*)actb + ((unsigned)S##1 * 128u + cpo)); \
    R##2 = *(const unsigned*)((const char*)actb + ((unsigned)S##2 * 128u + cpo)); \
    R##3 = *(const unsigned*)((const char*)actb + ((unsigned)S##3 * 128u + cpo)); \
    R##4 = *(const unsigned*)((const char*)actb + ((unsigned)S##4 * 128u + cpo)); \
    R##5 = *(const unsigned*)((const char*)actb + ((unsigned)S##5 * 128u + cpo)); \
    R##6 = *(const unsigned*)((const char*)actb + ((unsigned)S##6 * 128u + cpo)); \
    R##7 = *(const unsigned*)((const char*)actb + ((unsigned)S##7 * 128u + cpo)); \
} while (0)
#define FMA_BANK(R, G) do { \
    const float* ab_ = &salpha[wv][(G) * 64 + hq * 4]; \
    unsigned rr_[8] = {R##0, R##1, R##2, R##3, R##4, R##5, R##6, R##7}; \
    _Pragma("unroll") \
    for (int j_ = 0; j_ < 8; ++j_) { \
        floatx4 al_ = *(const floatx4*)(ab_ + j_ * 8); \
        floatx2 al01_ = __builtin_shufflevector(al_, al_, 0, 1); \
        floatx2 al23_ = __builtin_shufflevector(al_, al_, 2, 3); \
        floatx2 a2_ = up2(rr_[j_]); \
        pk_fma_lo(acc2[0], a2_, al01_); pk_fma_hi(acc2[1], a2_, al01_); \
        pk_fma_lo(acc2[2], a2_, al23_); pk_fma_hi(acc2[3], a2_, al23_); \
    } \
} while (0)
            LOAD_BANK(sA, rA, 0);
            int g = 0;
            while (true) {
                if (g + 1 < ng) LOAD_BANK(sB, rB, g + 1);
                FMA_BANK(rA, g);
                ++g; if (g >= ng) break;
                if (g + 1 < ng) LOAD_BANK(sA, rA, g + 1);
                FMA_BANK(rB, g);
                ++g; if (g >= ng) break;
            }
#undef LOAD_BANK
#undef FMA_BANK
        }
        {   // self edge
            unsigned sv = *(const unsigned*)((const char*)actb + ((unsigned)node * 128u + cpo));
            floatx2 a2 = up2(sv);
            floatx4 sa = *(const floatx4*)&sself[wv][hq * 4];
            floatx2 sa01 = __builtin_shufflevector(sa, sa, 0, 1);
            floatx2 sa23 = __builtin_shufflevector(sa, sa, 2, 3);
            pk_fma_lo(acc2[0], a2, sa01); pk_fma_hi(acc2[1], a2, sa01);
            pk_fma_lo(acc2[2], a2, sa23); pk_fma_hi(acc2[3], a2, sa23);
        }
        // stage to LDS agg row: k = (hq*4+j)*64 + 2cp
#pragma unroll
        for (int j = 0; j < 4; ++j)
            *(unsigned*)&aggt[wv][(hq * 4 + j) * 64 + 2 * cp] = pk2(acc2[j].x, acc2[j].y);
    } else {
        // ---- fallback (deg>64, rare): streaming two-pass, full-wave per edge ----
        float acc[NH] = {0.f, 0.f, 0.f, 0.f, 0.f, 0.f, 0.f, 0.f};
        float den = 0.f;
        for (int base = beg; base < end; base += 8) {
            int ei = base + slot;
            if (ei < end) {
                int s = csrc[ei];
                float e = es[s * NH + h] + edr;
                e = e > 0.f ? e : 0.2f * e;
                den += __expf(e - selfe);
            }
        }
        den += __shfl_xor(den, 8);
        den += __shfl_xor(den, 16);
        den += __shfl_xor(den, 32);
        const float invden = 1.f / (den + 1.f);
        for (int base = beg; base < end; base += 8) {
            int ei = base + slot;
            float al = 0.f; int sl = 0;
            if (ei < end) {
                sl = csrc[ei];
                float e = es[sl * NH + h] + edr;
                e = e > 0.f ? e : 0.2f * e;
                al = __expf(e - selfe) * invden;
            }
            salpha[wv][lane] = al;
            if (h == 0) ssrcs[wv][slot] = sl;
            int ecnt = end - base; if (ecnt > 8) ecnt = 8;
            for (int j = 0; j < ecnt; ++j) {
                int s = ssrcs[wv][j];
                float a = bf2f(actb[(long)s * 64 + lane]);
                floatx4 al0 = *(const floatx4*)&salpha[wv][j * 8];
                floatx4 al1 = *(const floatx4*)&salpha[wv][j * 8 + 4];
                acc[0] += al0[0] * a; acc[1] += al0[1] * a;
                acc[2] += al0[2] * a; acc[3] += al0[3] * a;
                acc[4] += al1[0] * a; acc[5] += al1[1] * a;
                acc[6] += al1[2] * a; acc[7] += al1[3] * a;
            }
        }
        {
            if (slot == 0) sself[wv][h] = invden;
            float a = bf2f(actb[(long)node * 64 + lane]);
            floatx4 s0 = *(const floatx4*)&sself[wv][0];
            floatx4 s1 = *(const floatx4*)&sself[wv][4];
            acc[0] += s0[0] * a; acc[1] += s0[1] * a;
            acc[2] += s0[2] * a; acc[3] += s0[3] * a;
            acc[4] += s1[0] * a; acc[5] += s1[1] * a;
            acc[6] += s1[2] * a; acc[7] += s1[3] * a;
        }
#pragma unroll
        for (int hh = 0; hh < NH; ++hh)
            aggt[wv][hh * 64 + lane] = (unsigned short)f2bf_bits(acc[hh]);
    }

    __syncthreads();

    // ================= MFMA projection: [16 x 512] @ [512 x 16*NCT], all rows valid ========
    const int lr = lane & 15, q = lane >> 4;
    const bool act = wv < NCT;
    floatx4 acc = {};
    if (act) {
#pragma unroll 4
        for (int k0 = 0; k0 < 512; k0 += 32) {
            bf16x8 a = __builtin_bit_cast(bf16x8,
                *(const short8*)&aggt[lr][k0 + q * 8]);
            bf16x8 b = __builtin_bit_cast(bf16x8,
                *(const short8*)((const short*)wgT + (long)(wv * 16 + lr) * 512 + k0 + q * 8));
            acc = __builtin_amdgcn_mfma_f32_16x16x32_bf16(a, b, acc, 0, 0, 0);
        }
    }

    if (EPI == 2) {
        if (act) {
#pragma unroll
            for (int r = 0; r < 4; ++r) {
                int onode = blockIdx.x * 16 + q * 4 + r;
                int col = wv * 16 + lr;
                float v = acc[r] * 0.125f + bias[col];
                ((bf16*)outp)[(long)onode * 64 + col] = __float2bfloat16(fmaxf(v, 0.f));
            }
        }
    } else {
        // log_softmax across 32 cols held by waves 0 (cols 0-15) and 1 (cols 16-31)
        float v[4], m[4];
#pragma unroll
        for (int r = 0; r < 4; ++r) {
            v[r] = acc[r] * 0.125f + (act ? bias[wv * 16 + lr] : 0.f);
            m[r] = v[r];
        }
#pragma unroll
        for (int off = 1; off < 16; off <<= 1)
#pragma unroll
            for (int r = 0; r < 4; ++r) m[r] = fmaxf(m[r], __shfl_xor(m[r], off));
        if (act && lr == 0) {
#pragma unroll
            for (int r = 0; r < 4; ++r) redbuf[0][wv][q * 4 + r] = m[r];
        }
        __syncthreads();
        float s[4];
#pragma unroll
        for (int r = 0; r < 4; ++r) {
            float mm_ = fmaxf(redbuf[0][0][q * 4 + r], redbuf[0][1][q * 4 + r]);
            m[r] = mm_;
            s[r] = act ? __expf(v[r] - mm_) : 0.f;
        }
#pragma unroll
        for (int off = 1; off < 16; off <<= 1)
#pragma unroll
            for (int r = 0; r < 4; ++r) s[r] += __shfl_xor(s[r], off);
        if (act && lr == 0) {
#pragma unroll
            for (int r = 0; r < 4; ++r) redbuf[1][wv][q * 4 + r] = s[r];
        }
        __syncthreads();
        if (act) {
#pragma unroll
            for (int r = 0; r < 4; ++r) {
                int row = q * 4 + r;
                int onode = blockIdx.x * 16 + row;
                float ls = m[r] + logf(redbuf[1][0][row] + redbuf[1][1][row]);
                ((float*)outp)[(long)onode * 32 + wv * 16 + lr] = v[r] - ls;
            }
        }
    }
}

// ---------------- launch ----------------
extern "C" void kernel_launch(void* const* d_in, const int* in_sizes, int n_in,
                              void* d_out, int out_size, void* d_ws, size_t ws_size,
                              hipStream_t stream) {
    const float* x        = (const float*)d_in[0];
    const int*   eidx     = (const int*)d_in[1];
    const float* gcn1_w   = (const float*)d_in[2];
    const float* gcn1_b   = (const float*)d_in[3];
    const float* bn1_g    = (const float*)d_in[4];
    const float* bn1_b    = (const float*)d_in[5];
    const float* bn1_m    = (const float*)d_in[6];
    const float* bn1_v    = (const float*)d_in[7];
    const float* gat1_w   = (const float*)d_in[8];
    const float* gat1_as  = (const float*)d_in[9];
    const float* gat1_ad  = (const float*)d_in[10];
    const float* gat1_b   = (const float*)d_in[11];
    const float* gcn2_w   = (const float*)d_in[12];
    const float* gcn2_b   = (const float*)d_in[13];
    const float* bn2_g    = (const float*)d_in[14];
    const float* bn2_b    = (const float*)d_in[15];
    const float* bn2_m    = (const float*)d_in[16];
    const float* bn2_v    = (const float*)d_in[17];
    const float* gat2_w   = (const float*)d_in[18];
    const float* gat2_as  = (const float*)d_in[19];
    const float* gat2_ad  = (const float*)d_in[20];
    const float* gat2_b   = (const float*)d_in[21];
    float* out = (float*)d_out;

    const int* esrc = eidx;
    const int* edst = eidx + NE;

    // workspace (~78 MB, < proven-safe 110.6 MB)
    float* ws = (float*)d_ws;
    int*      ghist  = (int*)ws;                        // GH
    int*      gpre   = ghist + GH;                      // GH
    int*      gbsum  = gpre + GH;                       // 512 (unscanned block sums)
    unsigned* ebuf   = (unsigned*)(gbsum + 512);        // NE
    int*      rowptr = (int*)(ebuf + NE);               // 50048
    int*      csrc   = rowptr + 50048;                  // NE
    float*    dinv   = (float*)(csrc + NE);             // 50048
    float*    es     = dinv + 50048;                    // 400000
    float*    ed     = es + 400000;                     // 400000
    float*    was1   = ed + 400000;                     // 512
    float*    wad1   = was1 + 512;                      // 512
    float*    was2   = wad1 + 512;                      // 512
    float*    wad2   = was2 + 512;                      // 512
    bf16*     wT1    = (bf16*)(wad2 + 512);             // 64*128
    bf16*     wT2    = wT1 + 64 * 128;                  // 64*64
    bf16*     wgT1   = wT2 + 64 * 64;                   // 64*512
    bf16*     wgT2   = wgT1 + 64 * 512;                 // 64*512
    bf16*     actb   = wgT2 + 64 * 512;                 // N*64 bf16
    bf16*     mmbf   = actb + (size_t)NN * 64;          // N*64 bf16
    bf16*     gact   = mmbf + (size_t)NN * 64;          // N*64 bf16

    auto cdiv = [](long a, long b) { return (int)((a + b - 1) / b); };
    const int GB = cdiv(NN, 64);
    const int NB = cdiv(NN, 4);
    const int FB = NN / 16;   // 3125 exact

    // ---- CSR build ----
    bin_count_prep_kernel<<<EBLK + PREPB, 256, 0, stream>>>(edst, ghist,
        gcn1_w, gcn2_w, gat1_w, gat2_w, gat1_as, gat1_ad, gat2_as, gat2_ad,
        wT1, wT2, wgT1, wgT2, was1, wad1, was2, wad2);
    scang1_kernel<<<GH / 256, 256, 0, stream>>>(ghist, gpre, gbsum, GH);
    bin_scatter_kernel<<<EBLK, 256, 0, stream>>>(esrc, edst, gpre, gbsum, ebuf);
    bucket_finalize_kernel<<<NBUK, 256, 0, stream>>>(ebuf, gpre, gbsum, rowptr, dinv, csrc);

    // ---- GCN1 (+ fused GAT1 scores) ----
    mm2_kernel<IND, 3, true><<<GB, 256, 0, stream>>>(x, wT1, mmbf, nullptr, dinv, NN, 64);
    gcn_fused_kernel<<<NB, 256, 0, stream>>>(rowptr, csrc, dinv, mmbf,
        gcn1_b, bn1_g, bn1_b, bn1_m, bn1_v, was1, wad1, actb, es, ed);

    // ---- GAT1 (C=64), fully fused ----
    gat_fused_kernel<4, 2><<<FB, 1024, 0, stream>>>(rowptr, csrc, es, ed, actb, wgT1, gat1_b, gact);

    // ---- GCN2 (+ fused GAT2 scores) ----
    mm2_kernel<64, 3, false><<<GB, 256, 0, stream>>>(gact, wT2, mmbf, nullptr, dinv, NN, 64);
    gcn_fused_kernel<<<NB, 256, 0, stream>>>(rowptr, csrc, dinv, mmbf,
        gcn2_b, bn2_g, bn2_b, bn2_m, bn2_v, was2, wad2, actb, es, ed);

    // ---- GAT2 (C=32) + fused log_softmax -> out ----
    gat_fused_kernel<2, 4><<<FB, 1024, 0, stream>>>(rowptr, csrc, es, ed, actb, wgT2, gat2_b, out);
}

// Round 13
// 347.511 us; speedup vs baseline: 1.1515x; 1.0214x over previous
//
#include <hip/hip_runtime.h>
#include <hip/hip_bf16.h>

#define NN 50000
#define NE 800000
#define IND 128
#define NH 8
#define EBLK 256          // binning blocks
#define EPB 3125          // NE / EBLK
#define NBUK 391          // buckets of 128 dst nodes
#define NBUKP 392         // padded (bucket 391 empty -> offset == NE)
#define GH (NBUKP * EBLK) // 100352
#define PREPB 308         // prep blocks: 78848 / 256

typedef __hip_bfloat16 bf16;
typedef __attribute__((ext_vector_type(8))) short short8;
typedef __attribute__((ext_vector_type(8))) __bf16 bf16x8;
typedef __attribute__((ext_vector_type(4))) float floatx4;
typedef __attribute__((ext_vector_type(2))) float floatx2;

static __device__ __forceinline__ short f2bf_bits(float f) {
    unsigned u = __float_as_uint(f);
    u = (u + 0x7fffu + ((u >> 16) & 1u)) >> 16;
    return (short)u;
}
static __device__ __forceinline__ float bf2f(bf16 v) { return __bfloat162float(v); }
static __device__ __forceinline__ floatx2 up2(unsigned av) {
    floatx2 r;
    r.x = __uint_as_float(av << 16);
    r.y = __uint_as_float(av & 0xffff0000u);
    return r;
}
static __device__ __forceinline__ unsigned pk2(float a, float b) {
    return (unsigned)(unsigned short)f2bf_bits(a) | ((unsigned)(unsigned short)f2bf_bits(b) << 16);
}
// acc.lo += a.lo * al.lo ; acc.hi += a.hi * al.lo   (broadcast LOW half of al)
static __device__ __forceinline__ void pk_fma_lo(floatx2& acc, floatx2 a, floatx2 al) {
    asm("v_pk_fma_f32 %0, %1, %2, %0 op_sel:[0,0,0] op_sel_hi:[1,0,1]"
        : "+v"(acc) : "v"(a), "v"(al));
}
// acc.lo += a.lo * al.hi ; acc.hi += a.hi * al.hi   (broadcast HIGH half of al)
static __device__ __forceinline__ void pk_fma_hi(floatx2& acc, floatx2 a, floatx2 al) {
    asm("v_pk_fma_f32 %0, %1, %2, %0 op_sel:[0,1,0] op_sel_hi:[1,1,1]"
        : "+v"(acc) : "v"(a), "v"(al));
}

// exclusive scan of bsum[0..NBUKP) into gb[0..512); mirrors scang1's proven pattern
static __device__ __forceinline__ void scan_buckets(const int* __restrict__ bsum,
        int* sp, int* gb, int tid) {
    int v0 = (2 * tid < NBUKP) ? bsum[2 * tid] : 0;
    int v1 = (2 * tid + 1 < NBUKP) ? bsum[2 * tid + 1] : 0;
    int c = v0 + v1;
    sp[tid] = c; __syncthreads();
    int val = c;
#pragma unroll
    for (int off = 1; off < 256; off <<= 1) {
        int t = (tid >= off) ? sp[tid - off] : 0;
        __syncthreads();
        val += t; sp[tid] = val;
        __syncthreads();
    }
    int pex = val - c;
    gb[2 * tid] = pex;
    gb[2 * tid + 1] = pex + v0;
    __syncthreads();
}

// ---------------- merged: edge bin counting (blocks 0..255) + weight prep (blocks 256..563) ----
__global__ __launch_bounds__(256) void bin_count_prep_kernel(const int* __restrict__ edst,
        int* __restrict__ ghist,
        const float* __restrict__ gcn1_w, const float* __restrict__ gcn2_w,
        const float* __restrict__ gat1_w, const float* __restrict__ gat2_w,
        const float* __restrict__ as1, const float* __restrict__ ad1,
        const float* __restrict__ as2, const float* __restrict__ ad2,
        bf16* __restrict__ wT1, bf16* __restrict__ wT2,
        bf16* __restrict__ wgT1, bf16* __restrict__ wgT2,
        float* __restrict__ was1, float* __restrict__ wad1,
        float* __restrict__ was2, float* __restrict__ wad2) {
    __shared__ int hsh[NBUKP];
    const int tid = threadIdx.x;
    if (blockIdx.x < EBLK) {
        const int blk = blockIdx.x;
        for (int b = tid; b < NBUKP; b += 256) hsh[b] = 0;
        __syncthreads();
        const int e0 = blk * EPB;
        for (int e = e0 + tid; e < e0 + EPB; e += 256)
            atomicAdd(&hsh[edst[e] >> 7], 1);
        __syncthreads();
        for (int b = tid; b < NBUKP; b += 256)
            ghist[b * EBLK + blk] = hsh[b];
    } else {
        int idx = (blockIdx.x - EBLK) * 256 + tid;
        if (idx < 8192) {
            int m = idx >> 7, k = idx & 127;
            ((short*)wT1)[idx] = f2bf_bits(gcn1_w[(long)k * 64 + m]);
        } else if (idx < 12288) {
            int i = idx - 8192;
            int m = i >> 6, k = i & 63;
            ((short*)wT2)[i] = f2bf_bits(gcn2_w[(long)k * 64 + m]);
        } else if (idx < 45056) {
            int i = idx - 12288;
            int m = i >> 9, k = i & 511;
            int h = k >> 6, c = k & 63;
            ((short*)wgT1)[i] = f2bf_bits(gat1_w[(long)c * 512 + h * 64 + m]);
        } else if (idx < 77824) {
            int i = idx - 45056;
            int m = i >> 9, k = i & 511;
            int h = k >> 6, c = k & 63;
            ((short*)wgT2)[i] = (m < 32) ? f2bf_bits(gat2_w[(long)c * 256 + h * 32 + m]) : (short)0;
        } else if (idx < 78336) {
            int i = idx - 77824;
            int h = i >> 6, c = i & 63;
            const float* wrow = gat1_w + (long)c * 512 + h * 64;
            float s = 0.f, d = 0.f;
            for (int cc = 0; cc < 64; ++cc) {
                float w = wrow[cc];
                s += w * as1[h * 64 + cc];
                d += w * ad1[h * 64 + cc];
            }
            was1[i] = s; wad1[i] = d;
        } else if (idx < 78848) {
            int i = idx - 78336;
            int h = i >> 6, c = i & 63;
            const float* wrow = gat2_w + (long)c * 256 + h * 32;
            float s = 0.f, d = 0.f;
            for (int cc = 0; cc < 32; ++cc) {
                float w = wrow[cc];
                s += w * as2[h * 32 + cc];
                d += w * ad2[h * 32 + cc];
            }
            was2[i] = s; wad2[i] = d;
        }
    }
}

__global__ __launch_bounds__(256) void scang1_kernel(const int* __restrict__ src,
        int* __restrict__ pre, int* __restrict__ bsum, int n) {
    __shared__ int sh[256];
    const int tid = threadIdx.x;
    const int idx = blockIdx.x * 256 + tid;
    int c = (idx < n) ? src[idx] : 0;
    sh[tid] = c; __syncthreads();
    int val = c;
#pragma unroll
    for (int off = 1; off < 256; off <<= 1) {
        int t = (tid >= off) ? sh[tid - off] : 0;
        __syncthreads();
        val += t; sh[tid] = val;
        __syncthreads();
    }
    if (idx < n) pre[idx] = val - c;
    if (tid == 255) bsum[blockIdx.x] = val;
}

// bin_scatter inlines the bucket-level scan (scang2 kernel removed)
__global__ __launch_bounds__(256) void bin_scatter_kernel(const int* __restrict__ esrc,
        const int* __restrict__ edst, const int* __restrict__ gpre,
        const int* __restrict__ bsum, unsigned* __restrict__ ebuf) {
    __shared__ int cur[NBUKP];
    __shared__ int sp[256], gb[512];
    const int tid = threadIdx.x, blk = blockIdx.x;
    scan_buckets(bsum, sp, gb, tid);
    for (int b = tid; b < NBUKP; b += 256)
        cur[b] = gpre[b * EBLK + blk] + gb[b];
    __syncthreads();
    const int e0 = blk * EPB;
    for (int e = e0 + tid; e < e0 + EPB; e += 256) {
        int d = edst[e], s = esrc[e];
        int pos = atomicAdd(&cur[d >> 7], 1);
        ebuf[pos] = ((unsigned)(d & 127) << 16) | (unsigned)s;
    }
}

__global__ __launch_bounds__(256) void bucket_finalize_kernel(const unsigned* __restrict__ ebuf,
        const int* __restrict__ gpre, const int* __restrict__ bsum,
        int* __restrict__ rowptr, float* __restrict__ dinv, int* __restrict__ csrc) {
    __shared__ int lh[128], lcur[128], sc[256];
    __shared__ int sp[256], gb[512];
    const int bu = blockIdx.x, tid = threadIdx.x;
    scan_buckets(bsum, sp, gb, tid);
    const int seg_beg = gpre[bu * EBLK] + gb[bu];
    const int seg_end = gpre[(bu + 1) * EBLK] + gb[bu + 1];
    if (tid < 128) lh[tid] = 0;
    __syncthreads();
    for (int i = seg_beg + tid; i < seg_end; i += 256)
        atomicAdd(&lh[ebuf[i] >> 16], 1);
    __syncthreads();
    int c = (tid < 128) ? lh[tid] : 0;
    sc[tid] = c; __syncthreads();
    int val = c;
#pragma unroll
    for (int off = 1; off < 256; off <<= 1) {
        int t = (tid >= off) ? sc[tid - off] : 0;
        __syncthreads();
        val += t; sc[tid] = val;
        __syncthreads();
    }
    int excl = val - c;
    if (tid < 128) {
        lcur[tid] = excl;
        int node = bu * 128 + tid;
        if (node < NN) {
            rowptr[node] = seg_beg + excl;
            dinv[node] = rsqrtf((float)c + 1.f);
        }
    }
    if (bu == 0 && tid == 0) rowptr[NN] = NE;
    __syncthreads();
    for (int i = seg_beg + tid; i < seg_end; i += 256) {
        unsigned u = ebuf[i];
        int pos = atomicAdd(&lcur[u >> 16], 1);
        csrc[seg_beg + pos] = (int)(u & 0xffffu);
    }
}

// ---------------- MFMA matmul v2: NO LDS ----------------
template<int K, int EPI, bool AF32>
__global__ __launch_bounds__(256) void mm2_kernel(const void* __restrict__ A,
        const bf16* __restrict__ wT, void* __restrict__ C,
        const float* __restrict__ bias, const float* __restrict__ rowscale,
        int nrows, int M) {
    const int row0 = blockIdx.x * 64;
    const int tid = threadIdx.x;
    const int lane = tid & 63, wave = tid >> 6;
    const int lr = lane & 15, q = lane >> 4;
    const int row = row0 + wave * 16 + lr;
    const bool rok = row < nrows;
    constexpr int NC = 4;
    floatx4 acc[NC] = {};
#pragma unroll 4
    for (int k0 = 0; k0 < K; k0 += 32) {
        short8 av = {0, 0, 0, 0, 0, 0, 0, 0};
        if (rok) {
            if (AF32) {
                const float* apf = (const float*)A + (long)row * K + q * 8 + k0;
                floatx4 va = *(const floatx4*)apf;
                floatx4 vb = *(const floatx4*)(apf + 4);
#pragma unroll
                for (int j = 0; j < 4; ++j) { av[j] = f2bf_bits(va[j]); av[4 + j] = f2bf_bits(vb[j]); }
            } else {
                av = *(const short8*)((const short*)A + (long)row * K + q * 8 + k0);
            }
        }
        bf16x8 a = __builtin_bit_cast(bf16x8, av);
#pragma unroll
        for (int c = 0; c < NC; ++c) {
            bf16x8 b = __builtin_bit_cast(bf16x8,
                *(const short8*)((const short*)wT + (long)(c * 16 + lr) * K + k0 + q * 8));
            acc[c] = __builtin_amdgcn_mfma_f32_16x16x32_bf16(a, b, acc[c], 0, 0, 0);
        }
    }
#pragma unroll
    for (int c = 0; c < NC; ++c)
#pragma unroll
        for (int r = 0; r < 4; ++r) {
            int orow = row0 + wave * 16 + q * 4 + r;
            int col = c * 16 + lr;
            if (orow < nrows && col < M) {
                long o = (long)orow * M + col;
                float v = acc[c][r];
                if (EPI == 0) ((float*)C)[o] = v;
                else if (EPI == 2) {
                    v = v * 0.125f + bias[col];
                    ((bf16*)C)[o] = __float2bfloat16(fmaxf(v, 0.f));
                } else {
                    ((bf16*)C)[o] = __float2bfloat16(rowscale[orow] * v);
                }
            }
        }
}

// -------- fused GCN aggregate + bias + BN + ReLU + GAT SCORES (es/ed) --------
__global__ __launch_bounds__(256) void gcn_fused_kernel(const int* __restrict__ rowptr,
        const int* __restrict__ csrc, const float* __restrict__ dinv,
        const bf16* __restrict__ hin, const float* __restrict__ b,
        const float* __restrict__ gamma, const float* __restrict__ beta,
        const float* __restrict__ mean, const float* __restrict__ var,
        const float* __restrict__ was, const float* __restrict__ wad,
        bf16* __restrict__ actout, float* __restrict__ es, float* __restrict__ ed) {
    __shared__ float swd[1024];   // [0..511] was, [512..1023] wad
    const int tid = threadIdx.x;
    for (int i = tid; i < 1024; i += 256)
        swd[i] = (i < 512) ? was[i] : wad[i - 512];
    __syncthreads();
    const int node = blockIdx.x * 4 + (tid >> 6);
    const int lane = tid & 63;
    const int eslot = lane >> 5, cp = lane & 31;
    const unsigned cpo = 4u * (unsigned)cp;
    const int beg = __builtin_amdgcn_readfirstlane(rowptr[node]);
    const int end = __builtin_amdgcn_readfirstlane(rowptr[node + 1]);
    const float di = dinv[node];
    const int* csp = csrc + beg;
    floatx2 acc2 = {0.f, 0.f};
    const int dn = end - beg;
    const int kup = (dn + 15) & ~15;
    for (int k0 = 0; k0 < kup; k0 += 16) {
        int s_[8]; float w_[8];
#pragma unroll
        for (int u = 0; u < 8; ++u) {
            int k = k0 + 2 * u + eslot;
            int ok = k < dn;
            s_[u] = csp[ok ? k : 0];
            w_[u] = ok ? 1.f : 0.f;
        }
        unsigned av_[8];
#pragma unroll
        for (int u = 0; u < 8; ++u)
            av_[u] = *(const unsigned*)((const char*)hin + ((unsigned)s_[u] * 128u + cpo));
#pragma unroll
        for (int u = 0; u < 8; ++u) {
            floatx2 a2 = up2(av_[u]);
            acc2 += a2 * w_[u];
        }
    }
    acc2.x += __shfl_xor(acc2.x, 32);
    acc2.y += __shfl_xor(acc2.y, 32);
    {
        unsigned sv = *(const unsigned*)((const char*)hin + ((unsigned)node * 128u + cpo));
        acc2 += up2(sv);
    }
    int c0 = 2 * cp, c1 = c0 + 1;
    float x0 = acc2.x * di + b[c0];
    float x1 = acc2.y * di + b[c1];
    x0 = (x0 - mean[c0]) * rsqrtf(var[c0] + 1e-5f) * gamma[c0] + beta[c0];
    x1 = (x1 - mean[c1]) * rsqrtf(var[c1] + 1e-5f) * gamma[c1] + beta[c1];
    float x0r = fmaxf(x0, 0.f), x1r = fmaxf(x1, 0.f);
    if (eslot == 0)
        *(unsigned*)((unsigned short*)actout + (long)node * 64 + c0) = pk2(x0r, x1r);
    // ---- fused scores: p[h] = sum_c act[c]*w[h*64+c]; eslot 0 -> es, eslot 1 -> ed ----
    const float* wsel = &swd[eslot << 9];
    float p0, p1, p2, p3, p4, p5, p6, p7;
    {
        floatx2 w;
#define SC(H, P) w = *(const floatx2*)&wsel[H * 64 + c0]; P = x0r * w.x + x1r * w.y;
        SC(0, p0) SC(1, p1) SC(2, p2) SC(3, p3) SC(4, p4) SC(5, p5) SC(6, p6) SC(7, p7)
#undef SC
    }
#pragma unroll
    for (int off = 1; off < 32; off <<= 1) {
        p0 += __shfl_xor(p0, off); p1 += __shfl_xor(p1, off);
        p2 += __shfl_xor(p2, off); p3 += __shfl_xor(p3, off);
        p4 += __shfl_xor(p4, off); p5 += __shfl_xor(p5, off);
        p6 += __shfl_xor(p6, off); p7 += __shfl_xor(p7, off);
    }
    if (cp == 0) {
        float* dst = eslot ? ed : es;
        floatx4 v0 = {p0, p1, p2, p3}, v1 = {p4, p5, p6, p7};
        *(floatx4*)&dst[(long)node * 8] = v0;
        *(floatx4*)&dst[(long)node * 8 + 4] = v1;
    }
}

// ---------------- FUSED GAT: 16 waves, 1 node/wave + full 16-row MFMA projection --------------
// R8-proven structure. EPI == 2 additionally fuses the downstream GCN2 transform (h1 @ W2,
// dinv-rowscaled) via a 2-MFMA second stage through a small LDS tile, writing mmbf directly
// (mm2<64> kernel eliminated). EPI == 4 unchanged (bias + log_softmax -> out).
template<int NCT, int EPI>
__global__ __launch_bounds__(1024) void gat_fused_kernel(const int* __restrict__ rowptr,
        const int* __restrict__ csrc, const float* __restrict__ es, const float* __restrict__ ed,
        const bf16* __restrict__ actb, const bf16* __restrict__ wgT,
        const float* __restrict__ bias, const bf16* __restrict__ wT2,
        const float* __restrict__ dinvp, void* __restrict__ outp) {
    __shared__ __align__(16) float salpha[16][512];
    __shared__ int ssrcs[16][64];
    __shared__ __align__(16) float sself[16][8];
    __shared__ __align__(16) unsigned short aggt[16][520];   // all 16 rows live
    __shared__ float redbuf[2][2][16];                        // [max|sum][ct][row]
    const int wv = threadIdx.x >> 6;
    const int lane = threadIdx.x & 63;
    const int h = lane & 7, slot = lane >> 3;
    const int hq = lane >> 5, cp = lane & 31;
    const unsigned cpo = 4u * (unsigned)cp;

    // ================= aggregation: ONE node per wave =================
    const int node = blockIdx.x * 16 + wv;
    const int beg = __builtin_amdgcn_readfirstlane(rowptr[node]);
    const int end = __builtin_amdgcn_readfirstlane(rowptr[node + 1]);
    const int deg = end - beg;
    const int* csp = csrc + beg;
    const float edr = *(const float*)((const char*)ed + ((unsigned)node * 32u + (unsigned)h * 4u));
    float selfe = *(const float*)((const char*)es + ((unsigned)node * 32u + (unsigned)h * 4u)) + edr;
    selfe = selfe > 0.f ? selfe : 0.2f * selfe;

    if (deg <= 64) {
        // ---- Phase A: independent clamped gathers, uniform-branch block skip ----
        const int nb = (deg + 7) >> 3;
        const int dm1 = (deg > 0) ? deg - 1 : 0;
        float ex_r[8]; int s_r[8];
        float den = 0.f;
#pragma unroll
        for (int b = 0; b < 8; ++b) { ex_r[b] = 0.f; s_r[b] = 0; }
        if (deg > 0) {
#pragma unroll
            for (int b = 0; b < 8; ++b)
                if (b < nb) {
                    int k = b * 8 + slot;
                    s_r[b] = csp[k < deg ? k : dm1];
                }
#pragma unroll
            for (int b = 0; b < 8; ++b)
                if (b < nb) {
                    float e = *(const float*)((const char*)es +
                              ((unsigned)s_r[b] * 32u + (unsigned)h * 4u)) + edr;
                    e = e > 0.f ? e : 0.2f * e;
                    float ex = __expf(e - selfe);
                    ex_r[b] = (b * 8 + slot < deg) ? ex : 0.f;
                    den += ex_r[b];
                }
        }
        den += __shfl_xor(den, 8);
        den += __shfl_xor(den, 16);
        den += __shfl_xor(den, 32);
        const float invden = 1.f / (den + 1.f);
#pragma unroll
        for (int b = 0; b < 8; ++b)
            if (b < nb) salpha[wv][b * 64 + lane] = ex_r[b] * invden;
        if (h == 0) {
#pragma unroll
            for (int b = 0; b < 8; ++b)
                if (b < nb) ssrcs[wv][b * 8 + slot] = s_r[b];
        }
        if (slot == 0) sself[wv][h] = invden;

        // ---- Phase B: (head-quad, channel-pair) gather, pipelined 8-edge groups ----
        floatx2 acc2[4] = {};
        const int ng = nb;
        if (ng > 0) {
            int sA0, sA1, sA2, sA3, sA4, sA5, sA6, sA7;
            int sB0, sB1, sB2, sB3, sB4, sB5, sB6, sB7;
            unsigned rA0, rA1, rA2, rA3, rA4, rA5, rA6, rA7;
            unsigned rB0, rB1, rB2, rB3, rB4, rB5, rB6, rB7;
#define LOAD_BANK(S, R, G) do { \
    const int* sp_ = &ssrcs[wv][(G) * 8]; \
    S##0 = sp_[0]; S##1 = sp_[1]; S##2 = sp_[2]; S##3 = sp_[3]; \
    S##4 = sp_[4]; S##5 = sp_[5]; S##6 = sp_[6]; S##7 = sp_[7]; \
    R##0 = *(const unsigned*)((const char*)actb + ((unsigned)S##0 * 128u + cpo)); \
    R##1 = *(const unsigned*)((const char*)actb + ((unsigned)S##1 * 128u + cpo)); \
    R##2 = *(const unsigned*)((const char*)actb + ((unsigned)S##2 * 128u + cpo)); \
    R##3 = *(const unsigned*)((const char*)actb + ((unsigned)S##3 * 128u + cpo)); \
    R##4 = *(const unsigned*)((const char*)actb + ((unsigned)S##4 * 128u + cpo)); \
    R##5 = *(const unsigned*)((const char*)actb + ((unsigned)S##5 * 128u + cpo)); \
    R##6 = *(const unsigned*)((const char*)actb + ((unsigned)S##6 * 128u + cpo)); \
    R##7 = *(const unsigned*)((const char*)actb + ((unsigned)S##7 * 128u + cpo)); \
} while (0)
#define FMA_BANK(R, G) do { \
    const float* ab_ = &salpha[wv][(G) * 64 + hq * 4]; \
    unsigned rr_[8] = {R##0, R##1, R##2, R##3, R##4, R##5, R##6, R##7}; \
    _Pragma("unroll") \
    for (int j_ = 0; j_ < 8; ++j_) { \
        floatx4 al_ = *(const floatx4*)(ab_ + j_ * 8); \
        floatx2 al01_ = __builtin_shufflevector(al_, al_, 0, 1); \
        floatx2 al23_ = __builtin_shufflevector(al_, al_, 2, 3); \
        floatx2 a2_ = up2(rr_[j_]); \
        pk_fma_lo(acc2[0], a2_, al01_); pk_fma_hi(acc2[1], a2_, al01_); \
        pk_fma_lo(acc2[2], a2_, al23_); pk_fma_hi(acc2[3], a2_, al23_); \
    } \
} while (0)
            LOAD_BANK(sA, rA, 0);
            int g = 0;
            while (true) {
                if (g + 1 < ng) LOAD_BANK(sB, rB, g + 1);
                FMA_BANK(rA, g);
                ++g; if (g >= ng) break;
                if (g + 1 < ng) LOAD_BANK(sA, rA, g + 1);
                FMA_BANK(rB, g);
                ++g; if (g >= ng) break;
            }
#undef LOAD_BANK
#undef FMA_BANK
        }
        {   // self edge
            unsigned sv = *(const unsigned*)((const char*)actb + ((unsigned)node * 128u + cpo));
            floatx2 a2 = up2(sv);
            floatx4 sa = *(const floatx4*)&sself[wv][hq * 4];
            floatx2 sa01 = __builtin_shufflevector(sa, sa, 0, 1);
            floatx2 sa23 = __builtin_shufflevector(sa, sa, 2, 3);
            pk_fma_lo(acc2[0], a2, sa01); pk_fma_hi(acc2[1], a2, sa01);
            pk_fma_lo(acc2[2], a2, sa23); pk_fma_hi(acc2[3], a2, sa23);
        }
        // stage to LDS agg row: k = (hq*4+j)*64 + 2cp
#pragma unroll
        for (int j = 0; j < 4; ++j)
            *(unsigned*)&aggt[wv][(hq * 4 + j) * 64 + 2 * cp] = pk2(acc2[j].x, acc2[j].y);
    } else {
        // ---- fallback (deg>64, rare): streaming two-pass, full-wave per edge ----
        float acc[NH] = {0.f, 0.f, 0.f, 0.f, 0.f, 0.f, 0.f, 0.f};
        float den = 0.f;
        for (int base = beg; base < end; base += 8) {
            int ei = base + slot;
            if (ei < end) {
                int s = csrc[ei];
                float e = es[s * NH + h] + edr;
                e = e > 0.f ? e : 0.2f * e;
                den += __expf(e - selfe);
            }
        }
        den += __shfl_xor(den, 8);
        den += __shfl_xor(den, 16);
        den += __shfl_xor(den, 32);
        const float invden = 1.f / (den + 1.f);
        for (int base = beg; base < end; base += 8) {
            int ei = base + slot;
            float al = 0.f; int sl = 0;
            if (ei < end) {
                sl = csrc[ei];
                float e = es[sl * NH + h] + edr;
                e = e > 0.f ? e : 0.2f * e;
                al = __expf(e - selfe) * invden;
            }
            salpha[wv][lane] = al;
            if (h == 0) ssrcs[wv][slot] = sl;
            int ecnt = end - base; if (ecnt > 8) ecnt = 8;
            for (int j = 0; j < ecnt; ++j) {
                int s = ssrcs[wv][j];
                float a = bf2f(actb[(long)s * 64 + lane]);
                floatx4 al0 = *(const floatx4*)&salpha[wv][j * 8];
                floatx4 al1 = *(const floatx4*)&salpha[wv][j * 8 + 4];
                acc[0] += al0[0] * a; acc[1] += al0[1] * a;
                acc[2] += al0[2] * a; acc[3] += al0[3] * a;
                acc[4] += al1[0] * a; acc[5] += al1[1] * a;
                acc[6] += al1[2] * a; acc[7] += al1[3] * a;
            }
        }
        {
            if (slot == 0) sself[wv][h] = invden;
            float a = bf2f(actb[(long)node * 64 + lane]);
            floatx4 s0 = *(const floatx4*)&sself[wv][0];
            floatx4 s1 = *(const floatx4*)&sself[wv][4];
            acc[0] += s0[0] * a; acc[1] += s0[1] * a;
            acc[2] += s0[2] * a; acc[3] += s0[3] * a;
            acc[4] += s1[0] * a; acc[5] += s1[1] * a;
            acc[6] += s1[2] * a; acc[7] += s1[3] * a;
        }
#pragma unroll
        for (int hh = 0; hh < NH; ++hh)
            aggt[wv][hh * 64 + lane] = (unsigned short)f2bf_bits(acc[hh]);
    }

    __syncthreads();

    // ================= MFMA projection: [16 x 512] @ [512 x 16*NCT], all rows valid ========
    const int lr = lane & 15, q = lane >> 4;
    const bool act = wv < NCT;
    floatx4 acc = {};
    if (act) {
#pragma unroll 4
        for (int k0 = 0; k0 < 512; k0 += 32) {
            bf16x8 a = __builtin_bit_cast(bf16x8,
                *(const short8*)&aggt[lr][k0 + q * 8]);
            bf16x8 b = __builtin_bit_cast(bf16x8,
                *(const short8*)((const short*)wgT + (long)(wv * 16 + lr) * 512 + k0 + q * 8));
            acc = __builtin_amdgcn_mfma_f32_16x16x32_bf16(a, b, acc, 0, 0, 0);
        }
    }

    if (EPI == 2) {
        // ---- stage h1 = relu(acc*0.125 + bias) as bf16 into LDS (reuses dead salpha) ----
        unsigned short* hrel = (unsigned short*)&salpha[0][0];   // [16][72] shorts
        if (act) {
#pragma unroll
            for (int r = 0; r < 4; ++r) {
                float v = acc[r] * 0.125f + bias[wv * 16 + lr];
                hrel[(q * 4 + r) * 72 + wv * 16 + lr] = (unsigned short)f2bf_bits(fmaxf(v, 0.f));
            }
        }
        __syncthreads();
        // ---- fused GCN2 transform: [16 x 64] @ [64 x 16-tile], 2 MFMAs/wave ----
        if (act) {
            floatx4 a2c = {};
#pragma unroll
            for (int k0 = 0; k0 < 64; k0 += 32) {
                bf16x8 a = __builtin_bit_cast(bf16x8,
                    *(const short8*)&hrel[lr * 72 + k0 + q * 8]);
                bf16x8 b = __builtin_bit_cast(bf16x8,
                    *(const short8*)((const short*)wT2 + (wv * 16 + lr) * 64 + k0 + q * 8));
                a2c = __builtin_amdgcn_mfma_f32_16x16x32_bf16(a, b, a2c, 0, 0, 0);
            }
#pragma unroll
            for (int r = 0; r < 4; ++r) {
                int onode = blockIdx.x * 16 + q * 4 + r;
                ((bf16*)outp)[(long)onode * 64 + wv * 16 + lr] =
                    __float2bfloat16(dinvp[onode] * a2c[r]);
            }
        }
    } else {
        // log_softmax across 32 cols held by waves 0 (cols 0-15) and 1 (cols 16-31)
        float v[4], m[4];
#pragma unroll
        for (int r = 0; r < 4; ++r) {
            v[r] = acc[r] * 0.125f + (act ? bias[wv * 16 + lr] : 0.f);
            m[r] = v[r];
        }
#pragma unroll
        for (int off = 1; off < 16; off <<= 1)
#pragma unroll
            for (int r = 0; r < 4; ++r) m[r] = fmaxf(m[r], __shfl_xor(m[r], off));
        if (act && lr == 0) {
#pragma unroll
            for (int r = 0; r < 4; ++r) redbuf[0][wv][q * 4 + r] = m[r];
        }
        __syncthreads();
        float s[4];
#pragma unroll
        for (int r = 0; r < 4; ++r) {
            float mm_ = fmaxf(redbuf[0][0][q * 4 + r], redbuf[0][1][q * 4 + r]);
            m[r] = mm_;
            s[r] = act ? __expf(v[r] - mm_) : 0.f;
        }
#pragma unroll
        for (int off = 1; off < 16; off <<= 1)
#pragma unroll
            for (int r = 0; r < 4; ++r) s[r] += __shfl_xor(s[r], off);
        if (act && lr == 0) {
#pragma unroll
            for (int r = 0; r < 4; ++r) redbuf[1][wv][q * 4 + r] = s[r];
        }
        __syncthreads();
        if (act) {
#pragma unroll
            for (int r = 0; r < 4; ++r) {
                int row = q * 4 + r;
                int onode = blockIdx.x * 16 + row;
                float ls = m[r] + logf(redbuf[1][0][row] + redbuf[1][1][row]);
                ((float*)outp)[(long)onode * 32 + wv * 16 + lr] = v[r] - ls;
            }
        }
    }
}

// ---------------- launch ----------------
extern "C" void kernel_launch(void* const* d_in, const int* in_sizes, int n_in,
                              void* d_out, int out_size, void* d_ws, size_t ws_size,
                              hipStream_t stream) {
    const float* x        = (const float*)d_in[0];
    const int*   eidx     = (const int*)d_in[1];
    const float* gcn1_w   = (const float*)d_in[2];
    const float* gcn1_b   = (const float*)d_in[3];
    const float* bn1_g    = (const float*)d_in[4];
    const float* bn1_b    = (const float*)d_in[5];
    const float* bn1_m    = (const float*)d_in[6];
    const float* bn1_v    = (const float*)d_in[7];
    const float* gat1_w   = (const float*)d_in[8];
    const float* gat1_as  = (const float*)d_in[9];
    const float* gat1_ad  = (const float*)d_in[10];
    const float* gat1_b   = (const float*)d_in[11];
    const float* gcn2_w   = (const float*)d_in[12];
    const float* gcn2_b   = (const float*)d_in[13];
    const float* bn2_g    = (const float*)d_in[14];
    const float* bn2_b    = (const float*)d_in[15];
    const float* bn2_m    = (const float*)d_in[16];
    const float* bn2_v    = (const float*)d_in[17];
    const float* gat2_w   = (const float*)d_in[18];
    const float* gat2_as  = (const float*)d_in[19];
    const float* gat2_ad  = (const float*)d_in[20];
    const float* gat2_b   = (const float*)d_in[21];
    float* out = (float*)d_out;

    const int* esrc = eidx;
    const int* edst = eidx + NE;

    // workspace (~78 MB, < proven-safe 110.6 MB)
    float* ws = (float*)d_ws;
    int*      ghist  = (int*)ws;                        // GH
    int*      gpre   = ghist + GH;                      // GH
    int*      gbsum  = gpre + GH;                       // 512 (unscanned block sums)
    unsigned* ebuf   = (unsigned*)(gbsum + 512);        // NE
    int*      rowptr = (int*)(ebuf + NE);               // 50048
    int*      csrc   = rowptr + 50048;                  // NE
    float*    dinv   = (float*)(csrc + NE);             // 50048
    float*    es     = dinv + 50048;                    // 400000
    float*    ed     = es + 400000;                     // 400000
    float*    was1   = ed + 400000;                     // 512
    float*    wad1   = was1 + 512;                      // 512
    float*    was2   = wad1 + 512;                      // 512
    float*    wad2   = was2 + 512;                      // 512
    bf16*     wT1    = (bf16*)(wad2 + 512);             // 64*128
    bf16*     wT2    = wT1 + 64 * 128;                  // 64*64
    bf16*     wgT1   = wT2 + 64 * 64;                   // 64*512
    bf16*     wgT2   = wgT1 + 64 * 512;                 // 64*512
    bf16*     actb   = wgT2 + 64 * 512;                 // N*64 bf16
    bf16*     mmbf   = actb + (size_t)NN * 64;          // N*64 bf16

    auto cdiv = [](long a, long b) { return (int)((a + b - 1) / b); };
    const int GB = cdiv(NN, 64);
    const int NB = cdiv(NN, 4);
    const int FB = NN / 16;   // 3125 exact

    // ---- CSR build ----
    bin_count_prep_kernel<<<EBLK + PREPB, 256, 0, stream>>>(edst, ghist,
        gcn1_w, gcn2_w, gat1_w, gat2_w, gat1_as, gat1_ad, gat2_as, gat2_ad,
        wT1, wT2, wgT1, wgT2, was1, wad1, was2, wad2);
    scang1_kernel<<<GH / 256, 256, 0, stream>>>(ghist, gpre, gbsum, GH);
    bin_scatter_kernel<<<EBLK, 256, 0, stream>>>(esrc, edst, gpre, gbsum, ebuf);
    bucket_finalize_kernel<<<NBUK, 256, 0, stream>>>(ebuf, gpre, gbsum, rowptr, dinv, csrc);

    // ---- GCN1 (+ fused GAT1 scores) ----
    mm2_kernel<IND, 3, true><<<GB, 256, 0, stream>>>(x, wT1, mmbf, nullptr, dinv, NN, 64);
    gcn_fused_kernel<<<NB, 256, 0, stream>>>(rowptr, csrc, dinv, mmbf,
        gcn1_b, bn1_g, bn1_b, bn1_m, bn1_v, was1, wad1, actb, es, ed);

    // ---- GAT1 (C=64) fused with GCN2 transform: writes mmbf directly (mm2<64> removed) ----
    gat_fused_kernel<4, 2><<<FB, 1024, 0, stream>>>(rowptr, csrc, es, ed, actb, wgT1,
        gat1_b, wT2, dinv, mmbf);

    // ---- GCN2 aggregation (+ fused GAT2 scores) ----
    gcn_fused_kernel<<<NB, 256, 0, stream>>>(rowptr, csrc, dinv, mmbf,
        gcn2_b, bn2_g, bn2_b, bn2_m, bn2_v, was2, wad2, actb, es, ed);

    // ---- GAT2 (C=32) + fused log_softmax -> out ----
    gat_fused_kernel<2, 4><<<FB, 1024, 0, stream>>>(rowptr, csrc, es, ed, actb, wgT2,
        gat2_b, nullptr, nullptr, out);
}